// Round 1
// 168.359 us; speedup vs baseline: 1.0712x; 1.0712x over previous
//
#include <hip/hip_runtime.h>
#include <math.h>

#define BB 128
#define MM 35
#define PSZ 224
#define PP (PSZ*PSZ)          // 50176
#define SIGN_PENALTY 10.0f
#define RECON_WEIGHT 0.4f
#define DEFOCUS_RAD 1.0f
#define EPS_F 1e-8f
#define INV2PI 0.15915494309189535f

// CT: 224 = 14*16.  n = 14*n2 + n1; k = 16*k1 + k2.
// R13 = R12 + structural fusion:
//   k_stage1: d=0/1 folded into one block (defocus applied as a 4-FMA complex
//             rotation of the base field — saves the second phase+mask read,
//             second sincos pass, and 2 of 4 barriers). S1 232->233 turns the
//             outer-phase 4-way LDS bank conflict into a free 2-way.
//   T layout: tile-major [img][tile14][h224][c16] — stage1 outer stores and
//             stage2 reads are 256B/wave contiguous; stage2's inner DFT reads
//             global directly (lane t reads dword t+224n), deleting the LDS
//             staging loop + 1 barrier. S2=20 -> outer reads exactly 2-way.
//   pack_bf2: v_cvt_pk_bf16_f32 (1 VALU) instead of 5-op bit-twiddle.
// Spill rule (R10/R11): >~32 floats of cross-phase state per thread = scratch
// spill. Atomic rule (R5-R7): no same-address finale atomics.

// ws layout (floats):
//   [1] z_loss  [2..4] mask^2 partials (3)
//   [2048 ..) phase [B][P][P] — dead after stage1; partials alias it
//   [T_OFF ..) T [2*B][14][224][16] packed bf16x2
#define WS_PHASE_OFF    2048
#define WS_T_OFF        (WS_PHASE_OFF + BB*PP)
#define N_PARTIALS      (14*BB*2)
#define S1 233            // stage1 LDS row stride (dwords) — odd: 2-way banks
#define S2 20             // stage2 LDS slot-row stride (dwords)

static constexpr float W16R[16] = {
    1.0f, 0.9238795325f, 0.7071067812f, 0.3826834324f, 0.0f,
    -0.3826834324f, -0.7071067812f, -0.9238795325f, -1.0f,
    -0.9238795325f, -0.7071067812f, -0.3826834324f, 0.0f,
    0.3826834324f, 0.7071067812f, 0.9238795325f};
static constexpr float W16I[16] = {
    0.0f, -0.3826834324f, -0.7071067812f, -0.9238795325f, -1.0f,
    -0.9238795325f, -0.7071067812f, -0.3826834324f, 0.0f,
    0.3826834324f, 0.7071067812f, 0.9238795325f, 1.0f,
    0.9238795325f, 0.7071067812f, 0.3826834324f};
static constexpr float W7R[7] = {
    1.0f, 0.6234898019f, -0.2225209340f, -0.9009688679f,
    -0.9009688679f, -0.2225209340f, 0.6234898019f};
static constexpr float W7I[7] = {
    0.0f, -0.7818314825f, -0.9749279122f, -0.4338837391f,
    0.4338837391f, 0.9749279122f, 0.7818314825f};
static constexpr float W14R[7] = {
    1.0f, 0.9009688679f, 0.6234898019f, 0.2225209340f, -0.2225209340f,
    -0.6234898019f, -0.9009688679f};
static constexpr float W14I[7] = {
    0.0f, -0.4338837391f, -0.7818314825f, -0.9749279122f, -0.9749279122f,
    -0.7818314825f, -0.4338837391f};

__device__ __forceinline__ float lincoord(int i) {
    return -1.0f + 2.0f * (float)i / (float)(PSZ - 1);
}
__device__ __forceinline__ void fast_sincos(float x, float* s, float* c) {
    float rv = x * INV2PI;
    rv -= floorf(rv);
    *s = __builtin_amdgcn_sinf(rv);
    *c = __builtin_amdgcn_cosf(rv);
}
__device__ __forceinline__ float2 wexp_neg(float frac) {
    float rv = -frac;
    rv -= floorf(rv);
    return make_float2(__builtin_amdgcn_cosf(rv), __builtin_amdgcn_sinf(rv));
}
__device__ __forceinline__ unsigned pack_bf2(float a, float b) {
    // D[15:0]=bf16(a), D[31:16]=bf16(b) — single VALU op (RNE)
    unsigned r;
    asm("v_cvt_pk_bf16_f32 %0, %1, %2" : "=v"(r) : "v"(a), "v"(b));
    return r;
}
__device__ __forceinline__ float2 unpack_bf2(unsigned v) {
    return make_float2(__uint_as_float(v << 16), __uint_as_float(v & 0xffff0000u));
}
__device__ __forceinline__ float2 cmul(float2 a, float2 b) {
    return make_float2(fmaf(a.x, b.x, -a.y * b.y), fmaf(a.x, b.y, a.y * b.x));
}
__device__ __forceinline__ float2 cmulc(float2 a, float wr, float wi) {
    return make_float2(fmaf(a.x, wr, -a.y * wi), fmaf(a.x, wi, a.y * wr));
}
__device__ __forceinline__ float2 cadd(float2 a, float2 b) {
    return make_float2(a.x + b.x, a.y + b.y);
}
__device__ __forceinline__ float2 csub(float2 a, float2 b) {
    return make_float2(a.x - b.x, a.y - b.y);
}
__device__ __forceinline__ void cfma(float& acc, float c, float v) {
    if (c == 0.f) return;
    if (c == 1.f)  { acc += v; return; }
    if (c == -1.f) { acc -= v; return; }
    acc = fmaf(c, v, acc);
}

// 8-pt forward DFT via conjugate-symmetric pairs.
__device__ __forceinline__ void dft8_sym(const float2* u, float2* X) {
    float2 a1 = cadd(u[1], u[7]), b1 = csub(u[1], u[7]);
    float2 a2 = cadd(u[2], u[6]), b2 = csub(u[2], u[6]);
    float2 a3 = cadd(u[3], u[5]), b3 = csub(u[3], u[5]);
    float2 s04 = cadd(u[0], u[4]), d04 = csub(u[0], u[4]);
    X[0] = cadd(cadd(s04, a1), cadd(a2, a3));
    X[4] = cadd(csub(s04, a1), csub(a2, a3));
    {
        float2 p = csub(s04, a2);
        float2 q = csub(b1, b3);
        X[2] = make_float2(p.x + q.y, p.y - q.x);
        X[6] = make_float2(p.x - q.y, p.y + q.x);
    }
#pragma unroll
    for (int m = 1; m <= 3; m += 2) {
        float Px = d04.x, Py = d04.y, Qx = 0.f, Qy = 0.f;
#pragma unroll
        for (int n = 1; n <= 3; n++) {
            const float cR = W16R[(2 * n * m) & 15], cI = W16I[(2 * n * m) & 15];
            const float2 a = (n == 1) ? a1 : (n == 2) ? a2 : a3;
            const float2 b = (n == 1) ? b1 : (n == 2) ? b2 : b3;
            cfma(Px, cR, a.x); cfma(Py, cR, a.y);
            cfma(Qx, cI, b.x); cfma(Qy, cI, b.y);
        }
        X[m]     = make_float2(Px - Qy, Py + Qx);
        X[8 - m] = make_float2(Px + Qy, Py - Qx);
    }
}

// 7-pt forward DFT via conjugate-symmetric pairs.
__device__ __forceinline__ void dft7_sym(const float2* x, float2* X) {
    float2 a1 = cadd(x[1], x[6]), b1 = csub(x[1], x[6]);
    float2 a2 = cadd(x[2], x[5]), b2 = csub(x[2], x[5]);
    float2 a3 = cadd(x[3], x[4]), b3 = csub(x[3], x[4]);
    X[0] = cadd(cadd(x[0], a1), cadd(a2, a3));
#pragma unroll
    for (int k = 1; k <= 3; k++) {
        float Px = x[0].x, Py = x[0].y, Qx = 0.f, Qy = 0.f;
#pragma unroll
        for (int n = 1; n <= 3; n++) {
            const float cR = W7R[(n * k) % 7], cI = W7I[(n * k) % 7];
            const float2 a = (n == 1) ? a1 : (n == 2) ? a2 : a3;
            const float2 b = (n == 1) ? b1 : (n == 2) ? b2 : b3;
            cfma(Px, cR, a.x); cfma(Py, cR, a.y);
            cfma(Qx, cI, b.x); cfma(Qy, cI, b.y);
        }
        X[k]     = make_float2(Px - Qy, Py + Qx);
        X[7 - k] = make_float2(Px + Qy, Py - Qx);
    }
}

// Inner 224-split: 16-pt DFT (radix-2 + sym-8) + W224^{n1*k} twiddle, in-place LDS.
__device__ __forceinline__ void inner16_sym(unsigned* __restrict__ xbuf,
                                            int base, int mul, int n1) {
    float2 x[16];
#pragma unroll
    for (int n = 0; n < 16; n++) x[n] = unpack_bf2(xbuf[base + (14 * n) * mul]);
    float2 u[8], v[8];
#pragma unroll
    for (int n = 0; n < 8; n++) {
        u[n] = cadd(x[n], x[n + 8]);
        float2 w = csub(x[n], x[n + 8]);
        v[n] = (n == 0) ? w : cmulc(w, W16R[n], W16I[n]);
    }
    float2 u1w = wexp_neg((float)n1 * (1.0f / 224.0f));
    float2 u2w = wexp_neg((float)n1 * (1.0f / 112.0f));
    {
        float2 Xe[8];
        dft8_sym(u, Xe);
        float2 cur = make_float2(1.f, 0.f);
#pragma unroll
        for (int m = 0; m < 8; m++) {
            float2 z = (m == 0) ? Xe[0] : cmul(Xe[m], cur);
            xbuf[base + (14 * (2 * m)) * mul] = pack_bf2(z.x, z.y);
            cur = cmul(cur, u2w);
        }
    }
    {
        float2 Xo[8];
        dft8_sym(v, Xo);
        float2 cur = u1w;
#pragma unroll
        for (int m = 0; m < 8; m++) {
            float2 z = cmul(Xo[m], cur);
            xbuf[base + (14 * (2 * m + 1)) * mul] = pack_bf2(z.x, z.y);
            cur = cmul(cur, u2w);
        }
    }
}

// Stage2 variant: reads directly from tile-major global T (coalesced:
// lane t reads dword t + 224n), writes results into LDS for the outer pass.
__device__ __forceinline__ void inner16_g2l(const unsigned* __restrict__ gin,
                                            unsigned* __restrict__ xs,
                                            int n1, int cc) {
    float2 x[16];
#pragma unroll
    for (int n = 0; n < 16; n++)
        x[n] = unpack_bf2(gin[224 * n + 16 * n1 + cc]);
    float2 u[8], v[8];
#pragma unroll
    for (int n = 0; n < 8; n++) {
        u[n] = cadd(x[n], x[n + 8]);
        float2 w = csub(x[n], x[n + 8]);
        v[n] = (n == 0) ? w : cmulc(w, W16R[n], W16I[n]);
    }
    float2 u1w = wexp_neg((float)n1 * (1.0f / 224.0f));
    float2 u2w = wexp_neg((float)n1 * (1.0f / 112.0f));
    unsigned* xb = xs + n1 * S2 + cc;
    {
        float2 Xe[8];
        dft8_sym(u, Xe);
        float2 cur = make_float2(1.f, 0.f);
#pragma unroll
        for (int m = 0; m < 8; m++) {
            float2 z = (m == 0) ? Xe[0] : cmul(Xe[m], cur);
            xb[(14 * (2 * m)) * S2] = pack_bf2(z.x, z.y);
            cur = cmul(cur, u2w);
        }
    }
    {
        float2 Xo[8];
        dft8_sym(v, Xo);
        float2 cur = u1w;
#pragma unroll
        for (int m = 0; m < 8; m++) {
            float2 z = cmul(Xo[m], cur);
            xb[(14 * (2 * m + 1)) * S2] = pack_bf2(z.x, z.y);
            cur = cmul(cur, u2w);
        }
    }
}

// ---------------- k_phase: grid (197, 4). x<196: phase GEMM (32 b each).
// x==196: y0 zloss, y1..3 mask^2 thirds.
__global__ __launch_bounds__(256) void k_phase(const float* __restrict__ pred,
                                               const float* __restrict__ target,
                                               const float* __restrict__ zern,
                                               const float* __restrict__ mask,
                                               float* __restrict__ phase,
                                               float* __restrict__ ws) {
    __shared__ float pl[32 * MM];
    __shared__ float red[256];
    int t = threadIdx.x;
    if (blockIdx.x == 196) {
        int y = blockIdx.y;
        float s = 0.f;
        if (y == 0) {
            for (int i = t; i < BB * MM; i += 256) {
                float p = pred[i], tg = target[i];
                float dd = p - tg;
                float w = (p * tg < 0.f) ? SIGN_PENALTY : 1.f;
                s = fmaf(dd * dd, w, s);
            }
        } else {
            const int F4 = PP / 4;
            int st = (y - 1) * 4182;
            int en = (y == 3) ? F4 : st + 4182;
            const float4* m4 = (const float4*)mask;
            for (int i = st + t; i < en; i += 256) {
                float4 v = m4[i];
                s = fmaf(v.x, v.x, s); s = fmaf(v.y, v.y, s);
                s = fmaf(v.z, v.z, s); s = fmaf(v.w, v.w, s);
            }
        }
        red[t] = s;
        __syncthreads();
        for (int st = 128; st > 0; st >>= 1) {
            if (t < st) red[t] += red[t + st];
            __syncthreads();
        }
        if (t == 0) {
            if (y == 0) ws[1] = red[0] / (float)(BB * MM);
            else        ws[1 + y] = red[0];
        }
        return;
    }
    int bg = blockIdx.y;
    for (int i = t; i < 32 * MM; i += 256) {
        int j = i / MM, m = i % MM;
        pl[i] = pred[(bg * 32 + j) * MM + m];
    }
    __syncthreads();
    int pix = blockIdx.x * 256 + t;
    float acc[32];
#pragma unroll
    for (int j = 0; j < 32; j++) acc[j] = 0.f;
    for (int m = 0; m < MM; m++) {
        float z = zern[m * PP + pix];
#pragma unroll
        for (int j = 0; j < 32; j++) acc[j] = fmaf(pl[j * MM + m], z, acc[j]);
    }
    float mk = mask[pix];
#pragma unroll
    for (int j = 0; j < 32; j++) phase[(size_t)(bg * 32 + j) * PP + pix] = acc[j] * mk;
}

// ---------------- stage 1: row DFTs, BOTH defocus planes per block ----------
// d1 field = d0 field rotated by e^{i*df} (4 FMA) — one phase/mask read,
// one sincos pass, 2 barriers for both planes. Tile-major T stores (256B/wave).
__global__ __launch_bounds__(256, 5) void k_stage1(const float* __restrict__ phase,
                                                   const float* __restrict__ mask,
                                                   unsigned* __restrict__ T) {
    __shared__ unsigned xs0[16 * S1];
    __shared__ unsigned xs1[16 * S1];
    int h0 = blockIdx.x * 16;
    int b = blockIdx.y;
    int t = threadIdx.x;

    const float* ph_base = phase + (size_t)b * PP + (size_t)h0 * PSZ;
    for (int idx = t; idx < 16 * PSZ; idx += 256) {
        int r = idx / PSZ, w = idx - r * PSZ;
        float ph = ph_base[r * PSZ + w];
        float mk = mask[(h0 + r) * PSZ + w];
        float sn, cs;
        fast_sincos(ph, &sn, &cs);
        float vy = lincoord(h0 + r), vx = lincoord(w);
        float df = DEFOCUS_RAD * (2.f * (vx * vx + vy * vy) - 1.f);
        float sd, cd;
        fast_sincos(df, &sd, &cd);
        float c0 = mk * cs, s0 = mk * sn;
        xs0[r * S1 + w] = pack_bf2(c0, s0);
        xs1[r * S1 + w] = pack_bf2(fmaf(c0, cd, -s0 * sd),
                                   fmaf(s0, cd,  c0 * sd));
    }
    __syncthreads();

    if (t < 224) {                    // inner: 16 rows x 14 n1, both planes
        int r = t / 14, n1 = t - (t / 14) * 14;
        inner16_sym(xs0, r * S1 + n1, 1, n1);
        inner16_sym(xs1, r * S1 + n1, 1, n1);
    }
    __syncthreads();

    {                                 // outer: 16 rows x 16 k2, both planes
        int r = t >> 4, k2 = t & 15;
#pragma unroll
        for (int dd = 0; dd < 2; dd++) {
            const unsigned* xr = (dd ? xs1 : xs0) + r * S1 + k2 * 14;
            int img = dd * BB + b;
            // tile-major: T[img][k1][h0+r][k2]
            unsigned* Tt = T + (((size_t)img * 14) * PSZ + (h0 + r)) * 16 + k2;
            float2 e[7], E[7], O[7];
#pragma unroll
            for (int n = 0; n < 7; n++) e[n] = unpack_bf2(xr[2 * n]);
            dft7_sym(e, E);
#pragma unroll
            for (int n = 0; n < 7; n++) e[n] = unpack_bf2(xr[2 * n + 1]);
            dft7_sym(e, O);
#pragma unroll
            for (int k1 = 0; k1 < 7; k1++) {
                float2 op = (k1 == 0) ? O[0] : cmulc(O[k1], W14R[k1], W14I[k1]);
                float2 s = cadd(E[k1], op), q = csub(E[k1], op);
                Tt[(size_t)k1 * (PSZ * 16)]       = pack_bf2(s.x, s.y);
                Tt[(size_t)(k1 + 7) * (PSZ * 16)] = pack_bf2(q.x, q.y);
            }
        }
    }
}

// ---------------- stage 2: column DFTs + in-register psf loss ----------------
// Inner DFT reads tile-major T directly from global (coalesced, LLC-hit),
// writes to LDS; outer consumes LDS transposed. 2 barriers total.
__global__ __launch_bounds__(256, 6) void k_stage2(const unsigned* __restrict__ T,
                                                   const float* __restrict__ psfs,
                                                   const float* __restrict__ ws,
                                                   float* __restrict__ partials) {
    __shared__ unsigned xs[224 * S2];
    __shared__ float red[4];
    int tile = blockIdx.x, b = blockIdx.y, d = blockIdx.z;
    int img = d * BB + b;
    int t = threadIdx.x;
    int k2o = t >> 4, c = t & 15;

    const unsigned* Tb = T + ((size_t)img * 14 + tile) * (PSZ * 16);
    const float* inp = psfs + ((size_t)b * 2 + d) * PP;
    int scol = 16 * ((tile + 7) % 14) + c;
    float pf[14];
#pragma unroll
    for (int j = 0; j < 7; j++) {
        pf[j]     = inp[(size_t)(112 + 16 * j + k2o) * PSZ + scol];
        pf[j + 7] = inp[(size_t)(16 * j + k2o) * PSZ + scol];
    }

    if (t < 224)                      // inner: 14 n1 x 16 c, global -> LDS
        inner16_g2l(Tb, xs, t >> 4, t & 15);
    __syncthreads();

    float m2 = ws[2] + ws[3] + ws[4];
    float inv_denom = 1.f / (m2 * (float)PP + EPS_F);  // Parseval denominator

    float lsum = 0.f;
    {                                 // outer: 16 k2 x 16 c, loss in-register
        float2 e[7], E[7], O[7];
#pragma unroll
        for (int n = 0; n < 7; n++) e[n] = unpack_bf2(xs[(k2o * 14 + 2 * n) * S2 + c]);
        dft7_sym(e, E);
#pragma unroll
        for (int n = 0; n < 7; n++) e[n] = unpack_bf2(xs[(k2o * 14 + 2 * n + 1) * S2 + c]);
        dft7_sym(e, O);
#pragma unroll
        for (int k1 = 0; k1 < 7; k1++) {
            float2 op = (k1 == 0) ? O[0] : cmulc(O[k1], W14R[k1], W14I[k1]);
            float2 s = cadd(E[k1], op), q = csub(E[k1], op);
            float ds = fmaf(s.x, s.x, s.y * s.y) * inv_denom - pf[k1];
            float dq = fmaf(q.x, q.x, q.y * q.y) * inv_denom - pf[k1 + 7];
            lsum = fmaf(ds, ds, lsum);
            lsum = fmaf(dq, dq, lsum);
        }
    }
#pragma unroll
    for (int off = 32; off > 0; off >>= 1)
        lsum += __shfl_down(lsum, off, 64);
    if ((t & 63) == 0) red[t >> 6] = lsum;
    __syncthreads();
    if (t == 0)
        partials[(blockIdx.z * BB + blockIdx.y) * 14 + blockIdx.x] =
            red[0] + red[1] + red[2] + red[3];
}

// ---------------- final ----------------
__global__ void k_final(const float* __restrict__ ws,
                        const float* __restrict__ partials,
                        float* __restrict__ out) {
    __shared__ float red[256];
    float s = 0.f;
    for (int i = threadIdx.x; i < N_PARTIALS; i += 256) s += partials[i];
    red[threadIdx.x] = s;
    __syncthreads();
    for (int st = 128; st > 0; st >>= 1) {
        if (threadIdx.x < st) red[threadIdx.x] += red[threadIdx.x + st];
        __syncthreads();
    }
    if (threadIdx.x == 0) {
        float recon = red[0] / (float)((size_t)BB * PP);
        out[0] = ws[1] + RECON_WEIGHT * recon;
    }
}

extern "C" void kernel_launch(void* const* d_in, const int* in_sizes, int n_in,
                              void* d_out, int out_size, void* d_ws, size_t ws_size,
                              hipStream_t stream) {
    const float* pred   = (const float*)d_in[0];
    const float* target = (const float*)d_in[1];
    const float* psfs   = (const float*)d_in[2];
    const float* zern   = (const float*)d_in[3];
    const float* mask   = (const float*)d_in[4];

    float*    ws       = (float*)d_ws;
    float*    phase    = ws + WS_PHASE_OFF;
    float*    partials = ws + WS_PHASE_OFF;   // aliases phase (dead after stage1)
    unsigned* T        = (unsigned*)(ws + WS_T_OFF);
    float*    out      = (float*)d_out;

    k_phase<<<dim3(197, 4), 256, 0, stream>>>(pred, target, zern, mask, phase, ws);
    k_stage1<<<dim3(14, BB), 256, 0, stream>>>(phase, mask, T);
    k_stage2<<<dim3(14, BB, 2), 256, 0, stream>>>(T, psfs, ws, partials);
    k_final<<<1, 256, 0, stream>>>(ws, partials, out);
}

// Round 2
// 162.684 us; speedup vs baseline: 1.1085x; 1.0349x over previous
//
#include <hip/hip_runtime.h>
#include <math.h>

#define BB 128
#define MM 35
#define PSZ 224
#define PP (PSZ*PSZ)          // 50176
#define SIGN_PENALTY 10.0f
#define RECON_WEIGHT 0.4f
#define DEFOCUS_RAD 1.0f
#define EPS_F 1e-8f
#define INV2PI 0.15915494309189535f

// CT: 224 = 14*16.  n = 14*n2 + n1; k = 16*k1 + k2.
// R14 = R13 + stage1 one-barrier restructure:
//   k_stage1: staging pass + its barrier DELETED. Inner thread (r,n1) loads
//             its own 16 pixels (cols n1+14n of row r) from global, computes
//             sincos + defocus rotation in registers (plane1 parked as 16
//             packed bf16x2 regs to stay under the VGPR cap), and runs both
//             inner-16 DFTs register-direct. LDS ops/block 21504 -> 7168;
//             barriers 2 -> 1. Plane0 skips a bf16 round-trip (precision up).
//   inner16_core shared by stage1 (reg-source) and stage2 (global-source).
// Prior structure (R13): d=0/1 fold via field rotation; tile-major T
// [img][tile14][h224][c16]; stage2 reads global direct; v_cvt_pk_bf16_f32.
// Spill rule (R10/R11): >~32 floats of cross-phase state per thread = scratch
// spill. Atomic rule (R5-R7): no same-address finale atomics.

// ws layout (floats):
//   [1] z_loss  [2..4] mask^2 partials (3)
//   [2048 ..) phase [B][P][P] — dead after stage1; partials alias it
//   [T_OFF ..) T [2*B][14][224][16] packed bf16x2
#define WS_PHASE_OFF    2048
#define WS_T_OFF        (WS_PHASE_OFF + BB*PP)
#define N_PARTIALS      (14*BB*2)
#define S1 233            // stage1 LDS row stride (dwords) — odd: 2-way banks
#define S2 20             // stage2 LDS slot-row stride (dwords)

static constexpr float W16R[16] = {
    1.0f, 0.9238795325f, 0.7071067812f, 0.3826834324f, 0.0f,
    -0.3826834324f, -0.7071067812f, -0.9238795325f, -1.0f,
    -0.9238795325f, -0.7071067812f, -0.3826834324f, 0.0f,
    0.3826834324f, 0.7071067812f, 0.9238795325f};
static constexpr float W16I[16] = {
    0.0f, -0.3826834324f, -0.7071067812f, -0.9238795325f, -1.0f,
    -0.9238795325f, -0.7071067812f, -0.3826834324f, 0.0f,
    0.3826834324f, 0.7071067812f, 0.9238795325f, 1.0f,
    0.9238795325f, 0.7071067812f, 0.3826834324f};
static constexpr float W7R[7] = {
    1.0f, 0.6234898019f, -0.2225209340f, -0.9009688679f,
    -0.9009688679f, -0.2225209340f, 0.6234898019f};
static constexpr float W7I[7] = {
    0.0f, -0.7818314825f, -0.9749279122f, -0.4338837391f,
    0.4338837391f, 0.9749279122f, 0.7818314825f};
static constexpr float W14R[7] = {
    1.0f, 0.9009688679f, 0.6234898019f, 0.2225209340f, -0.2225209340f,
    -0.6234898019f, -0.9009688679f};
static constexpr float W14I[7] = {
    0.0f, -0.4338837391f, -0.7818314825f, -0.9749279122f, -0.9749279122f,
    -0.7818314825f, -0.4338837391f};

__device__ __forceinline__ float lincoord(int i) {
    return -1.0f + 2.0f * (float)i / (float)(PSZ - 1);
}
__device__ __forceinline__ void fast_sincos(float x, float* s, float* c) {
    float rv = x * INV2PI;
    rv -= floorf(rv);
    *s = __builtin_amdgcn_sinf(rv);
    *c = __builtin_amdgcn_cosf(rv);
}
__device__ __forceinline__ float2 wexp_neg(float frac) {
    float rv = -frac;
    rv -= floorf(rv);
    return make_float2(__builtin_amdgcn_cosf(rv), __builtin_amdgcn_sinf(rv));
}
__device__ __forceinline__ unsigned pack_bf2(float a, float b) {
    // D[15:0]=bf16(a), D[31:16]=bf16(b) — single VALU op (RNE)
    unsigned r;
    asm("v_cvt_pk_bf16_f32 %0, %1, %2" : "=v"(r) : "v"(a), "v"(b));
    return r;
}
__device__ __forceinline__ float2 unpack_bf2(unsigned v) {
    return make_float2(__uint_as_float(v << 16), __uint_as_float(v & 0xffff0000u));
}
__device__ __forceinline__ float2 cmul(float2 a, float2 b) {
    return make_float2(fmaf(a.x, b.x, -a.y * b.y), fmaf(a.x, b.y, a.y * b.x));
}
__device__ __forceinline__ float2 cmulc(float2 a, float wr, float wi) {
    return make_float2(fmaf(a.x, wr, -a.y * wi), fmaf(a.x, wi, a.y * wr));
}
__device__ __forceinline__ float2 cadd(float2 a, float2 b) {
    return make_float2(a.x + b.x, a.y + b.y);
}
__device__ __forceinline__ float2 csub(float2 a, float2 b) {
    return make_float2(a.x - b.x, a.y - b.y);
}
__device__ __forceinline__ void cfma(float& acc, float c, float v) {
    if (c == 0.f) return;
    if (c == 1.f)  { acc += v; return; }
    if (c == -1.f) { acc -= v; return; }
    acc = fmaf(c, v, acc);
}

// 8-pt forward DFT via conjugate-symmetric pairs.
__device__ __forceinline__ void dft8_sym(const float2* u, float2* X) {
    float2 a1 = cadd(u[1], u[7]), b1 = csub(u[1], u[7]);
    float2 a2 = cadd(u[2], u[6]), b2 = csub(u[2], u[6]);
    float2 a3 = cadd(u[3], u[5]), b3 = csub(u[3], u[5]);
    float2 s04 = cadd(u[0], u[4]), d04 = csub(u[0], u[4]);
    X[0] = cadd(cadd(s04, a1), cadd(a2, a3));
    X[4] = cadd(csub(s04, a1), csub(a2, a3));
    {
        float2 p = csub(s04, a2);
        float2 q = csub(b1, b3);
        X[2] = make_float2(p.x + q.y, p.y - q.x);
        X[6] = make_float2(p.x - q.y, p.y + q.x);
    }
#pragma unroll
    for (int m = 1; m <= 3; m += 2) {
        float Px = d04.x, Py = d04.y, Qx = 0.f, Qy = 0.f;
#pragma unroll
        for (int n = 1; n <= 3; n++) {
            const float cR = W16R[(2 * n * m) & 15], cI = W16I[(2 * n * m) & 15];
            const float2 a = (n == 1) ? a1 : (n == 2) ? a2 : a3;
            const float2 b = (n == 1) ? b1 : (n == 2) ? b2 : b3;
            cfma(Px, cR, a.x); cfma(Py, cR, a.y);
            cfma(Qx, cI, b.x); cfma(Qy, cI, b.y);
        }
        X[m]     = make_float2(Px - Qy, Py + Qx);
        X[8 - m] = make_float2(Px + Qy, Py - Qx);
    }
}

// 7-pt forward DFT via conjugate-symmetric pairs.
__device__ __forceinline__ void dft7_sym(const float2* x, float2* X) {
    float2 a1 = cadd(x[1], x[6]), b1 = csub(x[1], x[6]);
    float2 a2 = cadd(x[2], x[5]), b2 = csub(x[2], x[5]);
    float2 a3 = cadd(x[3], x[4]), b3 = csub(x[3], x[4]);
    X[0] = cadd(cadd(x[0], a1), cadd(a2, a3));
#pragma unroll
    for (int k = 1; k <= 3; k++) {
        float Px = x[0].x, Py = x[0].y, Qx = 0.f, Qy = 0.f;
#pragma unroll
        for (int n = 1; n <= 3; n++) {
            const float cR = W7R[(n * k) % 7], cI = W7I[(n * k) % 7];
            const float2 a = (n == 1) ? a1 : (n == 2) ? a2 : a3;
            const float2 b = (n == 1) ? b1 : (n == 2) ? b2 : b3;
            cfma(Px, cR, a.x); cfma(Py, cR, a.y);
            cfma(Qx, cI, b.x); cfma(Qy, cI, b.y);
        }
        X[k]     = make_float2(Px - Qy, Py + Qx);
        X[7 - k] = make_float2(Px + Qy, Py - Qx);
    }
}

// Inner 224-split: 16-pt DFT (radix-2 + sym-8) + W224^{n1*k} twiddle.
// Source: registers. Dest: LDS, packed bf16x2, slot stride 14*mul dwords.
__device__ __forceinline__ void inner16_core(const float2* xin,
                                             unsigned* __restrict__ xbuf,
                                             int base, int mul, int n1) {
    float2 u[8], v[8];
#pragma unroll
    for (int n = 0; n < 8; n++) {
        u[n] = cadd(xin[n], xin[n + 8]);
        float2 w = csub(xin[n], xin[n + 8]);
        v[n] = (n == 0) ? w : cmulc(w, W16R[n], W16I[n]);
    }
    float2 u1w = wexp_neg((float)n1 * (1.0f / 224.0f));
    float2 u2w = wexp_neg((float)n1 * (1.0f / 112.0f));
    {
        float2 Xe[8];
        dft8_sym(u, Xe);
        float2 cur = make_float2(1.f, 0.f);
#pragma unroll
        for (int m = 0; m < 8; m++) {
            float2 z = (m == 0) ? Xe[0] : cmul(Xe[m], cur);
            xbuf[base + (14 * (2 * m)) * mul] = pack_bf2(z.x, z.y);
            cur = cmul(cur, u2w);
        }
    }
    {
        float2 Xo[8];
        dft8_sym(v, Xo);
        float2 cur = u1w;
#pragma unroll
        for (int m = 0; m < 8; m++) {
            float2 z = cmul(Xo[m], cur);
            xbuf[base + (14 * (2 * m + 1)) * mul] = pack_bf2(z.x, z.y);
            cur = cmul(cur, u2w);
        }
    }
}

// ---------------- k_phase: grid (197, 4). x<196: phase GEMM (32 b each).
// x==196: y0 zloss, y1..3 mask^2 thirds.
__global__ __launch_bounds__(256) void k_phase(const float* __restrict__ pred,
                                               const float* __restrict__ target,
                                               const float* __restrict__ zern,
                                               const float* __restrict__ mask,
                                               float* __restrict__ phase,
                                               float* __restrict__ ws) {
    __shared__ float pl[32 * MM];
    __shared__ float red[256];
    int t = threadIdx.x;
    if (blockIdx.x == 196) {
        int y = blockIdx.y;
        float s = 0.f;
        if (y == 0) {
            for (int i = t; i < BB * MM; i += 256) {
                float p = pred[i], tg = target[i];
                float dd = p - tg;
                float w = (p * tg < 0.f) ? SIGN_PENALTY : 1.f;
                s = fmaf(dd * dd, w, s);
            }
        } else {
            const int F4 = PP / 4;
            int st = (y - 1) * 4182;
            int en = (y == 3) ? F4 : st + 4182;
            const float4* m4 = (const float4*)mask;
            for (int i = st + t; i < en; i += 256) {
                float4 v = m4[i];
                s = fmaf(v.x, v.x, s); s = fmaf(v.y, v.y, s);
                s = fmaf(v.z, v.z, s); s = fmaf(v.w, v.w, s);
            }
        }
        red[t] = s;
        __syncthreads();
        for (int st = 128; st > 0; st >>= 1) {
            if (t < st) red[t] += red[t + st];
            __syncthreads();
        }
        if (t == 0) {
            if (y == 0) ws[1] = red[0] / (float)(BB * MM);
            else        ws[1 + y] = red[0];
        }
        return;
    }
    int bg = blockIdx.y;
    for (int i = t; i < 32 * MM; i += 256) {
        int j = i / MM, m = i % MM;
        pl[i] = pred[(bg * 32 + j) * MM + m];
    }
    __syncthreads();
    int pix = blockIdx.x * 256 + t;
    float acc[32];
#pragma unroll
    for (int j = 0; j < 32; j++) acc[j] = 0.f;
    for (int m = 0; m < MM; m++) {
        float z = zern[m * PP + pix];
#pragma unroll
        for (int j = 0; j < 32; j++) acc[j] = fmaf(pl[j * MM + m], z, acc[j]);
    }
    float mk = mask[pix];
#pragma unroll
    for (int j = 0; j < 32; j++) phase[(size_t)(bg * 32 + j) * PP + pix] = acc[j] * mk;
}

// ---------------- stage 1: row DFTs, BOTH planes, ONE barrier ---------------
// Inner thread (r,n1) owns pixels (row r, cols n1+14n): loads them from
// global, sincos + defocus-rotation in registers (plane1 parked bf16x2),
// runs both inner-16 DFTs register-direct into LDS. Then one barrier, outer.
__global__ __launch_bounds__(256, 5) void k_stage1(const float* __restrict__ phase,
                                                   const float* __restrict__ mask,
                                                   unsigned* __restrict__ T) {
    __shared__ unsigned xs0[16 * S1];
    __shared__ unsigned xs1[16 * S1];
    int h0 = blockIdx.x * 16;
    int b = blockIdx.y;
    int t = threadIdx.x;

    if (t < 224) {
        int r = t / 14, n1 = t - (t / 14) * 14;
        const float* phr = phase + (size_t)b * PP + (size_t)(h0 + r) * PSZ;
        const float* mkr = mask + (size_t)(h0 + r) * PSZ;
        float vy = lincoord(h0 + r);
        float vy2m1 = DEFOCUS_RAD * (2.f * vy * vy - 1.f);
        float2 x0[16];
        unsigned x1p[16];
#pragma unroll
        for (int n = 0; n < 16; n++) {
            int col = n1 + 14 * n;
            float ph = phr[col];
            float mk = mkr[col];
            float sn, cs;
            fast_sincos(ph, &sn, &cs);
            float vx = lincoord(col);
            float df = fmaf(2.f * DEFOCUS_RAD, vx * vx, vy2m1);
            float sd, cd;
            fast_sincos(df, &sd, &cd);
            float c0 = mk * cs, s0 = mk * sn;
            x0[n] = make_float2(c0, s0);
            x1p[n] = pack_bf2(fmaf(c0, cd, -s0 * sd), fmaf(s0, cd, c0 * sd));
        }
        inner16_core(x0, xs0, r * S1 + n1, 1, n1);
        float2 x1[16];
#pragma unroll
        for (int n = 0; n < 16; n++) x1[n] = unpack_bf2(x1p[n]);
        inner16_core(x1, xs1, r * S1 + n1, 1, n1);
    }
    __syncthreads();

    {                                 // outer: 16 rows x 16 k2, both planes
        int r = t >> 4, k2 = t & 15;
#pragma unroll
        for (int dd = 0; dd < 2; dd++) {
            const unsigned* xr = (dd ? xs1 : xs0) + r * S1 + k2 * 14;
            int img = dd * BB + b;
            // tile-major: T[img][k1][h0+r][k2]
            unsigned* Tt = T + (((size_t)img * 14) * PSZ + (h0 + r)) * 16 + k2;
            float2 e[7], E[7], O[7];
#pragma unroll
            for (int n = 0; n < 7; n++) e[n] = unpack_bf2(xr[2 * n]);
            dft7_sym(e, E);
#pragma unroll
            for (int n = 0; n < 7; n++) e[n] = unpack_bf2(xr[2 * n + 1]);
            dft7_sym(e, O);
#pragma unroll
            for (int k1 = 0; k1 < 7; k1++) {
                float2 op = (k1 == 0) ? O[0] : cmulc(O[k1], W14R[k1], W14I[k1]);
                float2 s = cadd(E[k1], op), q = csub(E[k1], op);
                Tt[(size_t)k1 * (PSZ * 16)]       = pack_bf2(s.x, s.y);
                Tt[(size_t)(k1 + 7) * (PSZ * 16)] = pack_bf2(q.x, q.y);
            }
        }
    }
}

// ---------------- stage 2: column DFTs + in-register psf loss ----------------
// Inner DFT reads tile-major T directly from global (coalesced, LLC-hit),
// writes to LDS; outer consumes LDS transposed. 2 barriers total.
__global__ __launch_bounds__(256, 6) void k_stage2(const unsigned* __restrict__ T,
                                                   const float* __restrict__ psfs,
                                                   const float* __restrict__ ws,
                                                   float* __restrict__ partials) {
    __shared__ unsigned xs[224 * S2];
    __shared__ float red[4];
    int tile = blockIdx.x, b = blockIdx.y, d = blockIdx.z;
    int img = d * BB + b;
    int t = threadIdx.x;
    int k2o = t >> 4, c = t & 15;

    const unsigned* Tb = T + ((size_t)img * 14 + tile) * (PSZ * 16);
    const float* inp = psfs + ((size_t)b * 2 + d) * PP;
    int scol = 16 * ((tile + 7) % 14) + c;
    float pf[14];
#pragma unroll
    for (int j = 0; j < 7; j++) {
        pf[j]     = inp[(size_t)(112 + 16 * j + k2o) * PSZ + scol];
        pf[j + 7] = inp[(size_t)(16 * j + k2o) * PSZ + scol];
    }

    if (t < 224) {                    // inner: 14 n1 x 16 c, global -> LDS
        int n1 = t >> 4, cc = t & 15;
        float2 x[16];
#pragma unroll
        for (int n = 0; n < 16; n++)
            x[n] = unpack_bf2(Tb[224 * n + t]);
        inner16_core(x, xs, n1 * S2 + cc, S2, n1);
    }
    __syncthreads();

    float m2 = ws[2] + ws[3] + ws[4];
    float inv_denom = 1.f / (m2 * (float)PP + EPS_F);  // Parseval denominator

    float lsum = 0.f;
    {                                 // outer: 16 k2 x 16 c, loss in-register
        float2 e[7], E[7], O[7];
#pragma unroll
        for (int n = 0; n < 7; n++) e[n] = unpack_bf2(xs[(k2o * 14 + 2 * n) * S2 + c]);
        dft7_sym(e, E);
#pragma unroll
        for (int n = 0; n < 7; n++) e[n] = unpack_bf2(xs[(k2o * 14 + 2 * n + 1) * S2 + c]);
        dft7_sym(e, O);
#pragma unroll
        for (int k1 = 0; k1 < 7; k1++) {
            float2 op = (k1 == 0) ? O[0] : cmulc(O[k1], W14R[k1], W14I[k1]);
            float2 s = cadd(E[k1], op), q = csub(E[k1], op);
            float ds = fmaf(s.x, s.x, s.y * s.y) * inv_denom - pf[k1];
            float dq = fmaf(q.x, q.x, q.y * q.y) * inv_denom - pf[k1 + 7];
            lsum = fmaf(ds, ds, lsum);
            lsum = fmaf(dq, dq, lsum);
        }
    }
#pragma unroll
    for (int off = 32; off > 0; off >>= 1)
        lsum += __shfl_down(lsum, off, 64);
    if ((t & 63) == 0) red[t >> 6] = lsum;
    __syncthreads();
    if (t == 0)
        partials[(blockIdx.z * BB + blockIdx.y) * 14 + blockIdx.x] =
            red[0] + red[1] + red[2] + red[3];
}

// ---------------- final ----------------
__global__ void k_final(const float* __restrict__ ws,
                        const float* __restrict__ partials,
                        float* __restrict__ out) {
    __shared__ float red[256];
    float s = 0.f;
    for (int i = threadIdx.x; i < N_PARTIALS; i += 256) s += partials[i];
    red[threadIdx.x] = s;
    __syncthreads();
    for (int st = 128; st > 0; st >>= 1) {
        if (threadIdx.x < st) red[threadIdx.x] += red[threadIdx.x + st];
        __syncthreads();
    }
    if (threadIdx.x == 0) {
        float recon = red[0] / (float)((size_t)BB * PP);
        out[0] = ws[1] + RECON_WEIGHT * recon;
    }
}

extern "C" void kernel_launch(void* const* d_in, const int* in_sizes, int n_in,
                              void* d_out, int out_size, void* d_ws, size_t ws_size,
                              hipStream_t stream) {
    const float* pred   = (const float*)d_in[0];
    const float* target = (const float*)d_in[1];
    const float* psfs   = (const float*)d_in[2];
    const float* zern   = (const float*)d_in[3];
    const float* mask   = (const float*)d_in[4];

    float*    ws       = (float*)d_ws;
    float*    phase    = ws + WS_PHASE_OFF;
    float*    partials = ws + WS_PHASE_OFF;   // aliases phase (dead after stage1)
    unsigned* T        = (unsigned*)(ws + WS_T_OFF);
    float*    out      = (float*)d_out;

    k_phase<<<dim3(197, 4), 256, 0, stream>>>(pred, target, zern, mask, phase, ws);
    k_stage1<<<dim3(14, BB), 256, 0, stream>>>(phase, mask, T);
    k_stage2<<<dim3(14, BB, 2), 256, 0, stream>>>(T, psfs, ws, partials);
    k_final<<<1, 256, 0, stream>>>(ws, partials, out);
}

// Round 3
// 154.616 us; speedup vs baseline: 1.1664x; 1.0522x over previous
//
#include <hip/hip_runtime.h>
#include <math.h>

#define BB 128
#define MM 35
#define PSZ 224
#define PP (PSZ*PSZ)          // 50176
#define SIGN_PENALTY 10.0f
#define RECON_WEIGHT 0.4f
#define DEFOCUS_RAD 1.0f
#define EPS_F 1e-8f
#define INV2PI 0.15915494309189535f

// CT: 224 = 14*16.  n = 14*n2 + n1; k = 16*k1 + k2.
// R15 = R14 + three issue/stall cuts:
//   k_phase: pl stride 35->36 (16B chunks) + m-chunked-by-4 loop ->
//            ds_read_b128: 1120 ds_read_b32 -> 288 b128 per thread (4x fewer
//            LDS instrs on the GEMM critical loop). Also folds mask+sincos:
//            writes packed bf16x2 plane-0 FIELD (same 4B/px as f32 phase).
//   k_stage1: reads field (1 u32/px) instead of phase+mask (2 f32/px) —
//            -25.7MB traffic, -16 sincos pairs/thread. launch_bounds (256,5)
//            ->(256,4): LDS caps at 5 blocks/CU anyway; VGPR cap 102->128
//            removes cross-phase spill (x0[16]+x1p[16] ~ 100+ regs).
//   k_stage2: T loads issued before pf prefetch (T is the critical path);
//            bounds (256,6)->(256,5) (VGPR cap 85->102, natural ~90).
// Prior structure: d=0/1 fold via field rotation; tile-major T
// [img][tile14][h224][c16]; stage2 reads global direct; v_cvt_pk_bf16_f32.
// Spill rule (R10/R11): >~32 floats of cross-phase state per thread = scratch
// spill. Atomic rule (R5-R7): no same-address finale atomics.

// ws layout (floats):
//   [1] z_loss  [2..4] mask^2 partials (3)
//   [2048 ..) field [B][P][P] packed bf16x2 — dead after stage1; partials alias
//   [T_OFF ..) T [2*B][14][224][16] packed bf16x2
#define WS_PHASE_OFF    2048
#define WS_T_OFF        (WS_PHASE_OFF + BB*PP)
#define N_PARTIALS      (14*BB*2)
#define S1 233            // stage1 LDS row stride (dwords) — odd: 2-way banks
#define S2 20             // stage2 LDS slot-row stride (dwords)

static constexpr float W16R[16] = {
    1.0f, 0.9238795325f, 0.7071067812f, 0.3826834324f, 0.0f,
    -0.3826834324f, -0.7071067812f, -0.9238795325f, -1.0f,
    -0.9238795325f, -0.7071067812f, -0.3826834324f, 0.0f,
    0.3826834324f, 0.7071067812f, 0.9238795325f};
static constexpr float W16I[16] = {
    0.0f, -0.3826834324f, -0.7071067812f, -0.9238795325f, -1.0f,
    -0.9238795325f, -0.7071067812f, -0.3826834324f, 0.0f,
    0.3826834324f, 0.7071067812f, 0.9238795325f, 1.0f,
    0.9238795325f, 0.7071067812f, 0.3826834324f};
static constexpr float W7R[7] = {
    1.0f, 0.6234898019f, -0.2225209340f, -0.9009688679f,
    -0.9009688679f, -0.2225209340f, 0.6234898019f};
static constexpr float W7I[7] = {
    0.0f, -0.7818314825f, -0.9749279122f, -0.4338837391f,
    0.4338837391f, 0.9749279122f, 0.7818314825f};
static constexpr float W14R[7] = {
    1.0f, 0.9009688679f, 0.6234898019f, 0.2225209340f, -0.2225209340f,
    -0.6234898019f, -0.9009688679f};
static constexpr float W14I[7] = {
    0.0f, -0.4338837391f, -0.7818314825f, -0.9749279122f, -0.9749279122f,
    -0.7818314825f, -0.4338837391f};

__device__ __forceinline__ float lincoord(int i) {
    return -1.0f + 2.0f * (float)i / (float)(PSZ - 1);
}
__device__ __forceinline__ void fast_sincos(float x, float* s, float* c) {
    float rv = x * INV2PI;
    rv -= floorf(rv);
    *s = __builtin_amdgcn_sinf(rv);
    *c = __builtin_amdgcn_cosf(rv);
}
__device__ __forceinline__ float2 wexp_neg(float frac) {
    float rv = -frac;
    rv -= floorf(rv);
    return make_float2(__builtin_amdgcn_cosf(rv), __builtin_amdgcn_sinf(rv));
}
__device__ __forceinline__ unsigned pack_bf2(float a, float b) {
    // D[15:0]=bf16(a), D[31:16]=bf16(b) — single VALU op (RNE)
    unsigned r;
    asm("v_cvt_pk_bf16_f32 %0, %1, %2" : "=v"(r) : "v"(a), "v"(b));
    return r;
}
__device__ __forceinline__ float2 unpack_bf2(unsigned v) {
    return make_float2(__uint_as_float(v << 16), __uint_as_float(v & 0xffff0000u));
}
__device__ __forceinline__ float2 cmul(float2 a, float2 b) {
    return make_float2(fmaf(a.x, b.x, -a.y * b.y), fmaf(a.x, b.y, a.y * b.x));
}
__device__ __forceinline__ float2 cmulc(float2 a, float wr, float wi) {
    return make_float2(fmaf(a.x, wr, -a.y * wi), fmaf(a.x, wi, a.y * wr));
}
__device__ __forceinline__ float2 cadd(float2 a, float2 b) {
    return make_float2(a.x + b.x, a.y + b.y);
}
__device__ __forceinline__ float2 csub(float2 a, float2 b) {
    return make_float2(a.x - b.x, a.y - b.y);
}
__device__ __forceinline__ void cfma(float& acc, float c, float v) {
    if (c == 0.f) return;
    if (c == 1.f)  { acc += v; return; }
    if (c == -1.f) { acc -= v; return; }
    acc = fmaf(c, v, acc);
}

// 8-pt forward DFT via conjugate-symmetric pairs.
__device__ __forceinline__ void dft8_sym(const float2* u, float2* X) {
    float2 a1 = cadd(u[1], u[7]), b1 = csub(u[1], u[7]);
    float2 a2 = cadd(u[2], u[6]), b2 = csub(u[2], u[6]);
    float2 a3 = cadd(u[3], u[5]), b3 = csub(u[3], u[5]);
    float2 s04 = cadd(u[0], u[4]), d04 = csub(u[0], u[4]);
    X[0] = cadd(cadd(s04, a1), cadd(a2, a3));
    X[4] = cadd(csub(s04, a1), csub(a2, a3));
    {
        float2 p = csub(s04, a2);
        float2 q = csub(b1, b3);
        X[2] = make_float2(p.x + q.y, p.y - q.x);
        X[6] = make_float2(p.x - q.y, p.y + q.x);
    }
#pragma unroll
    for (int m = 1; m <= 3; m += 2) {
        float Px = d04.x, Py = d04.y, Qx = 0.f, Qy = 0.f;
#pragma unroll
        for (int n = 1; n <= 3; n++) {
            const float cR = W16R[(2 * n * m) & 15], cI = W16I[(2 * n * m) & 15];
            const float2 a = (n == 1) ? a1 : (n == 2) ? a2 : a3;
            const float2 b = (n == 1) ? b1 : (n == 2) ? b2 : b3;
            cfma(Px, cR, a.x); cfma(Py, cR, a.y);
            cfma(Qx, cI, b.x); cfma(Qy, cI, b.y);
        }
        X[m]     = make_float2(Px - Qy, Py + Qx);
        X[8 - m] = make_float2(Px + Qy, Py - Qx);
    }
}

// 7-pt forward DFT via conjugate-symmetric pairs.
__device__ __forceinline__ void dft7_sym(const float2* x, float2* X) {
    float2 a1 = cadd(x[1], x[6]), b1 = csub(x[1], x[6]);
    float2 a2 = cadd(x[2], x[5]), b2 = csub(x[2], x[5]);
    float2 a3 = cadd(x[3], x[4]), b3 = csub(x[3], x[4]);
    X[0] = cadd(cadd(x[0], a1), cadd(a2, a3));
#pragma unroll
    for (int k = 1; k <= 3; k++) {
        float Px = x[0].x, Py = x[0].y, Qx = 0.f, Qy = 0.f;
#pragma unroll
        for (int n = 1; n <= 3; n++) {
            const float cR = W7R[(n * k) % 7], cI = W7I[(n * k) % 7];
            const float2 a = (n == 1) ? a1 : (n == 2) ? a2 : a3;
            const float2 b = (n == 1) ? b1 : (n == 2) ? b2 : b3;
            cfma(Px, cR, a.x); cfma(Py, cR, a.y);
            cfma(Qx, cI, b.x); cfma(Qy, cI, b.y);
        }
        X[k]     = make_float2(Px - Qy, Py + Qx);
        X[7 - k] = make_float2(Px + Qy, Py - Qx);
    }
}

// Inner 224-split: 16-pt DFT (radix-2 + sym-8) + W224^{n1*k} twiddle.
// Source: registers. Dest: LDS, packed bf16x2, slot stride 14*mul dwords.
__device__ __forceinline__ void inner16_core(const float2* xin,
                                             unsigned* __restrict__ xbuf,
                                             int base, int mul, int n1) {
    float2 u[8], v[8];
#pragma unroll
    for (int n = 0; n < 8; n++) {
        u[n] = cadd(xin[n], xin[n + 8]);
        float2 w = csub(xin[n], xin[n + 8]);
        v[n] = (n == 0) ? w : cmulc(w, W16R[n], W16I[n]);
    }
    float2 u1w = wexp_neg((float)n1 * (1.0f / 224.0f));
    float2 u2w = wexp_neg((float)n1 * (1.0f / 112.0f));
    {
        float2 Xe[8];
        dft8_sym(u, Xe);
        float2 cur = make_float2(1.f, 0.f);
#pragma unroll
        for (int m = 0; m < 8; m++) {
            float2 z = (m == 0) ? Xe[0] : cmul(Xe[m], cur);
            xbuf[base + (14 * (2 * m)) * mul] = pack_bf2(z.x, z.y);
            cur = cmul(cur, u2w);
        }
    }
    {
        float2 Xo[8];
        dft8_sym(v, Xo);
        float2 cur = u1w;
#pragma unroll
        for (int m = 0; m < 8; m++) {
            float2 z = cmul(Xo[m], cur);
            xbuf[base + (14 * (2 * m + 1)) * mul] = pack_bf2(z.x, z.y);
            cur = cmul(cur, u2w);
        }
    }
}

// ---------------- k_phase: grid (197, 4). x<196: phase GEMM (32 b each),
// writes packed bf16x2 plane-0 field. x==196: y0 zloss, y1..3 mask^2 thirds.
__global__ __launch_bounds__(256) void k_phase(const float* __restrict__ pred,
                                               const float* __restrict__ target,
                                               const float* __restrict__ zern,
                                               const float* __restrict__ mask,
                                               unsigned* __restrict__ field,
                                               float* __restrict__ ws) {
    __shared__ __align__(16) float pl[32 * 36];  // stride 36: 16B-aligned quads
    __shared__ float red[256];
    int t = threadIdx.x;
    if (blockIdx.x == 196) {
        int y = blockIdx.y;
        float s = 0.f;
        if (y == 0) {
            for (int i = t; i < BB * MM; i += 256) {
                float p = pred[i], tg = target[i];
                float dd = p - tg;
                float w = (p * tg < 0.f) ? SIGN_PENALTY : 1.f;
                s = fmaf(dd * dd, w, s);
            }
        } else {
            const int F4 = PP / 4;
            int st = (y - 1) * 4182;
            int en = (y == 3) ? F4 : st + 4182;
            const float4* m4 = (const float4*)mask;
            for (int i = st + t; i < en; i += 256) {
                float4 v = m4[i];
                s = fmaf(v.x, v.x, s); s = fmaf(v.y, v.y, s);
                s = fmaf(v.z, v.z, s); s = fmaf(v.w, v.w, s);
            }
        }
        red[t] = s;
        __syncthreads();
        for (int st = 128; st > 0; st >>= 1) {
            if (t < st) red[t] += red[t + st];
            __syncthreads();
        }
        if (t == 0) {
            if (y == 0) ws[1] = red[0] / (float)(BB * MM);
            else        ws[1 + y] = red[0];
        }
        return;
    }
    int bg = blockIdx.y;
    for (int i = t; i < 32 * MM; i += 256) {
        int j = i / MM, m = i - (i / MM) * MM;
        pl[j * 36 + m] = pred[(bg * 32 + j) * MM + m];
    }
    if (t < 32) pl[t * 36 + 35] = 0.f;   // pad slot (never multiplied)
    __syncthreads();
    int pix = blockIdx.x * 256 + t;
    float acc[32];
#pragma unroll
    for (int j = 0; j < 32; j++) acc[j] = 0.f;
    const float4* pl4 = (const float4*)pl;     // pl4[j*9 + mb/4]
    for (int mb = 0; mb < 32; mb += 4) {       // 8 chunks of 4 modes
        float z0 = zern[(size_t)(mb + 0) * PP + pix];
        float z1 = zern[(size_t)(mb + 1) * PP + pix];
        float z2 = zern[(size_t)(mb + 2) * PP + pix];
        float z3 = zern[(size_t)(mb + 3) * PP + pix];
#pragma unroll
        for (int j = 0; j < 32; j++) {
            float4 p4 = pl4[j * 9 + (mb >> 2)];
            acc[j] = fmaf(p4.x, z0, acc[j]);
            acc[j] = fmaf(p4.y, z1, acc[j]);
            acc[j] = fmaf(p4.z, z2, acc[j]);
            acc[j] = fmaf(p4.w, z3, acc[j]);
        }
    }
    {                                          // tail: modes 32..34
        float z0 = zern[(size_t)32 * PP + pix];
        float z1 = zern[(size_t)33 * PP + pix];
        float z2 = zern[(size_t)34 * PP + pix];
#pragma unroll
        for (int j = 0; j < 32; j++) {
            float4 p4 = pl4[j * 9 + 8];
            acc[j] = fmaf(p4.x, z0, acc[j]);
            acc[j] = fmaf(p4.y, z1, acc[j]);
            acc[j] = fmaf(p4.z, z2, acc[j]);
        }
    }
    float mk = mask[pix];
#pragma unroll
    for (int j = 0; j < 32; j++) {
        float ph = acc[j] * mk;
        float sn, cs;
        fast_sincos(ph, &sn, &cs);
        field[(size_t)(bg * 32 + j) * PP + pix] = pack_bf2(mk * cs, mk * sn);
    }
}

// ---------------- stage 1: row DFTs, BOTH planes, ONE barrier ---------------
// Inner thread (r,n1) owns pixels (row r, cols n1+14n): loads packed field,
// defocus-rotates for plane1 (parked bf16x2), runs both inner-16 DFTs
// register-direct into LDS. Then one barrier, outer DFT + tile-major T store.
__global__ __launch_bounds__(256, 4) void k_stage1(const unsigned* __restrict__ field,
                                                   unsigned* __restrict__ T) {
    __shared__ unsigned xs0[16 * S1];
    __shared__ unsigned xs1[16 * S1];
    int h0 = blockIdx.x * 16;
    int b = blockIdx.y;
    int t = threadIdx.x;

    if (t < 224) {
        int r = t / 14, n1 = t - (t / 14) * 14;
        const unsigned* fr = field + (size_t)b * PP + (size_t)(h0 + r) * PSZ;
        float vy = lincoord(h0 + r);
        float vy2m1 = DEFOCUS_RAD * (2.f * vy * vy - 1.f);
        float2 x0[16];
        unsigned x1p[16];
#pragma unroll
        for (int n = 0; n < 16; n++) {
            int col = n1 + 14 * n;
            float2 f = unpack_bf2(fr[col]);
            float vx = lincoord(col);
            float df = fmaf(2.f * DEFOCUS_RAD, vx * vx, vy2m1);
            float sd, cd;
            fast_sincos(df, &sd, &cd);
            x0[n] = f;
            x1p[n] = pack_bf2(fmaf(f.x, cd, -f.y * sd), fmaf(f.y, cd, f.x * sd));
        }
        inner16_core(x0, xs0, r * S1 + n1, 1, n1);
        float2 x1[16];
#pragma unroll
        for (int n = 0; n < 16; n++) x1[n] = unpack_bf2(x1p[n]);
        inner16_core(x1, xs1, r * S1 + n1, 1, n1);
    }
    __syncthreads();

    {                                 // outer: 16 rows x 16 k2, both planes
        int r = t >> 4, k2 = t & 15;
#pragma unroll
        for (int dd = 0; dd < 2; dd++) {
            const unsigned* xr = (dd ? xs1 : xs0) + r * S1 + k2 * 14;
            int img = dd * BB + b;
            // tile-major: T[img][k1][h0+r][k2]
            unsigned* Tt = T + (((size_t)img * 14) * PSZ + (h0 + r)) * 16 + k2;
            float2 e[7], E[7], O[7];
#pragma unroll
            for (int n = 0; n < 7; n++) e[n] = unpack_bf2(xr[2 * n]);
            dft7_sym(e, E);
#pragma unroll
            for (int n = 0; n < 7; n++) e[n] = unpack_bf2(xr[2 * n + 1]);
            dft7_sym(e, O);
#pragma unroll
            for (int k1 = 0; k1 < 7; k1++) {
                float2 op = (k1 == 0) ? O[0] : cmulc(O[k1], W14R[k1], W14I[k1]);
                float2 s = cadd(E[k1], op), q = csub(E[k1], op);
                Tt[(size_t)k1 * (PSZ * 16)]       = pack_bf2(s.x, s.y);
                Tt[(size_t)(k1 + 7) * (PSZ * 16)] = pack_bf2(q.x, q.y);
            }
        }
    }
}

// ---------------- stage 2: column DFTs + in-register psf loss ----------------
// Inner DFT reads tile-major T directly from global (coalesced, LLC-hit),
// writes to LDS; outer consumes LDS transposed. T loads issued first.
__global__ __launch_bounds__(256, 5) void k_stage2(const unsigned* __restrict__ T,
                                                   const float* __restrict__ psfs,
                                                   const float* __restrict__ ws,
                                                   float* __restrict__ partials) {
    __shared__ unsigned xs[224 * S2];
    __shared__ float red[4];
    int tile = blockIdx.x, b = blockIdx.y, d = blockIdx.z;
    int img = d * BB + b;
    int t = threadIdx.x;
    int k2o = t >> 4, c = t & 15;
    bool act = t < 224;

    const unsigned* Tb = T + ((size_t)img * 14 + tile) * (PSZ * 16);
    const float* inp = psfs + ((size_t)b * 2 + d) * PP;
    int scol = 16 * ((tile + 7) % 14) + c;

    unsigned xr[16];                  // T loads first: they gate the barrier
    if (act) {
#pragma unroll
        for (int n = 0; n < 16; n++) xr[n] = Tb[224 * n + t];
    }
    float pf[14];
#pragma unroll
    for (int j = 0; j < 7; j++) {
        pf[j]     = inp[(size_t)(112 + 16 * j + k2o) * PSZ + scol];
        pf[j + 7] = inp[(size_t)(16 * j + k2o) * PSZ + scol];
    }

    if (act) {                        // inner: 14 n1 x 16 c, reg -> LDS
        float2 x[16];
#pragma unroll
        for (int n = 0; n < 16; n++) x[n] = unpack_bf2(xr[n]);
        inner16_core(x, xs, (t >> 4) * S2 + (t & 15), S2, t >> 4);
    }
    __syncthreads();

    float m2 = ws[2] + ws[3] + ws[4];
    float inv_denom = 1.f / (m2 * (float)PP + EPS_F);  // Parseval denominator

    float lsum = 0.f;
    {                                 // outer: 16 k2 x 16 c, loss in-register
        float2 e[7], E[7], O[7];
#pragma unroll
        for (int n = 0; n < 7; n++) e[n] = unpack_bf2(xs[(k2o * 14 + 2 * n) * S2 + c]);
        dft7_sym(e, E);
#pragma unroll
        for (int n = 0; n < 7; n++) e[n] = unpack_bf2(xs[(k2o * 14 + 2 * n + 1) * S2 + c]);
        dft7_sym(e, O);
#pragma unroll
        for (int k1 = 0; k1 < 7; k1++) {
            float2 op = (k1 == 0) ? O[0] : cmulc(O[k1], W14R[k1], W14I[k1]);
            float2 s = cadd(E[k1], op), q = csub(E[k1], op);
            float ds = fmaf(s.x, s.x, s.y * s.y) * inv_denom - pf[k1];
            float dq = fmaf(q.x, q.x, q.y * q.y) * inv_denom - pf[k1 + 7];
            lsum = fmaf(ds, ds, lsum);
            lsum = fmaf(dq, dq, lsum);
        }
    }
#pragma unroll
    for (int off = 32; off > 0; off >>= 1)
        lsum += __shfl_down(lsum, off, 64);
    if ((t & 63) == 0) red[t >> 6] = lsum;
    __syncthreads();
    if (t == 0)
        partials[(blockIdx.z * BB + blockIdx.y) * 14 + blockIdx.x] =
            red[0] + red[1] + red[2] + red[3];
}

// ---------------- final ----------------
__global__ void k_final(const float* __restrict__ ws,
                        const float* __restrict__ partials,
                        float* __restrict__ out) {
    __shared__ float red[256];
    float s = 0.f;
    for (int i = threadIdx.x; i < N_PARTIALS; i += 256) s += partials[i];
    red[threadIdx.x] = s;
    __syncthreads();
    for (int st = 128; st > 0; st >>= 1) {
        if (threadIdx.x < st) red[threadIdx.x] += red[threadIdx.x + st];
        __syncthreads();
    }
    if (threadIdx.x == 0) {
        float recon = red[0] / (float)((size_t)BB * PP);
        out[0] = ws[1] + RECON_WEIGHT * recon;
    }
}

extern "C" void kernel_launch(void* const* d_in, const int* in_sizes, int n_in,
                              void* d_out, int out_size, void* d_ws, size_t ws_size,
                              hipStream_t stream) {
    const float* pred   = (const float*)d_in[0];
    const float* target = (const float*)d_in[1];
    const float* psfs   = (const float*)d_in[2];
    const float* zern   = (const float*)d_in[3];
    const float* mask   = (const float*)d_in[4];

    float*    ws       = (float*)d_ws;
    unsigned* field    = (unsigned*)(ws + WS_PHASE_OFF);
    float*    partials = ws + WS_PHASE_OFF;   // aliases field (dead after stage1)
    unsigned* T        = (unsigned*)(ws + WS_T_OFF);
    float*    out      = (float*)d_out;

    k_phase<<<dim3(197, 4), 256, 0, stream>>>(pred, target, zern, mask, field, ws);
    k_stage1<<<dim3(14, BB), 256, 0, stream>>>(field, T);
    k_stage2<<<dim3(14, BB, 2), 256, 0, stream>>>(T, psfs, ws, partials);
    k_final<<<1, 256, 0, stream>>>(ws, partials, out);
}

// Round 4
// 153.014 us; speedup vs baseline: 1.1786x; 1.0105x over previous
//
#include <hip/hip_runtime.h>
#include <math.h>

#define BB 128
#define MM 35
#define PSZ 224
#define PP (PSZ*PSZ)          // 50176
#define SIGN_PENALTY 10.0f
#define RECON_WEIGHT 0.4f
#define DEFOCUS_RAD 1.0f
#define EPS_F 1e-8f
#define INV2PI 0.15915494309189535f

// CT: 224 = 14*16.  n = 14*n2 + n1; k = 16*k1 + k2.
// R16 = R15 + stage1 plane-split + separable defocus tables:
//   defocus: theta(px) = [2D*vx^2-D] + [2D*vy^2] -> e^{i theta} =
//            ctab[col]*rtab[row]; two 224-entry f32 complex tables in the ws
//            header (ws[16..960), 3.6KB — no footprint growth), computed by
//            k_phase's x==196/y==0 block. Stage1 d=1: 2 cmul/px (8 FMA)
//            replaces a sincos pair (2 quarter-rate trans + reduce) — and at
//            FULL f32 precision (better than R15).
//   k_stage1: planes now independent -> grid (14, 2, BB) (d adjacent for L2
//            field reuse), ONE plane per block: LDS 29.8->14.9KB, VGPR
//            ~110->~80, launch_bounds (256,4)->(256,5) = 20 waves/CU,
//            halved pre-barrier critical path, 2x blocks for tail overlap.
// Prior structure: k_phase GEMM via pl stride-36 b128 + bf16x2 plane-0 field;
// tile-major T [img][tile14][h224][c16]; stage2 global-direct + in-reg loss;
// v_cvt_pk_bf16_f32. Spill rule (R10/R11): >~32 floats cross-phase state =
// scratch. Atomic rule (R5-R7): no same-address finale atomics.

// ws layout (floats):
//   [1] z_loss  [2..4] mask^2 partials (3)
//   [16..464)  ctab: 224 x float2 e^{i(2D vx^2 - D)}
//   [512..960) rtab: 224 x float2 e^{i(2D vy^2)}
//   [2048 ..) field [B][P][P] packed bf16x2 — dead after stage1; partials alias
//   [T_OFF ..) T [2*B][14][224][16] packed bf16x2
#define WS_PHASE_OFF    2048
#define WS_T_OFF        (WS_PHASE_OFF + BB*PP)
#define N_PARTIALS      (14*BB*2)
#define S1 233            // stage1 LDS row stride (dwords) — odd: 2-way banks
#define S2 20             // stage2 LDS slot-row stride (dwords)

static constexpr float W16R[16] = {
    1.0f, 0.9238795325f, 0.7071067812f, 0.3826834324f, 0.0f,
    -0.3826834324f, -0.7071067812f, -0.9238795325f, -1.0f,
    -0.9238795325f, -0.7071067812f, -0.3826834324f, 0.0f,
    0.3826834324f, 0.7071067812f, 0.9238795325f};
static constexpr float W16I[16] = {
    0.0f, -0.3826834324f, -0.7071067812f, -0.9238795325f, -1.0f,
    -0.9238795325f, -0.7071067812f, -0.3826834324f, 0.0f,
    0.3826834324f, 0.7071067812f, 0.9238795325f, 1.0f,
    0.9238795325f, 0.7071067812f, 0.3826834324f};
static constexpr float W7R[7] = {
    1.0f, 0.6234898019f, -0.2225209340f, -0.9009688679f,
    -0.9009688679f, -0.2225209340f, 0.6234898019f};
static constexpr float W7I[7] = {
    0.0f, -0.7818314825f, -0.9749279122f, -0.4338837391f,
    0.4338837391f, 0.9749279122f, 0.7818314825f};
static constexpr float W14R[7] = {
    1.0f, 0.9009688679f, 0.6234898019f, 0.2225209340f, -0.2225209340f,
    -0.6234898019f, -0.9009688679f};
static constexpr float W14I[7] = {
    0.0f, -0.4338837391f, -0.7818314825f, -0.9749279122f, -0.9749279122f,
    -0.7818314825f, -0.4338837391f};

__device__ __forceinline__ float lincoord(int i) {
    return -1.0f + 2.0f * (float)i / (float)(PSZ - 1);
}
__device__ __forceinline__ void fast_sincos(float x, float* s, float* c) {
    float rv = x * INV2PI;
    rv -= floorf(rv);
    *s = __builtin_amdgcn_sinf(rv);
    *c = __builtin_amdgcn_cosf(rv);
}
__device__ __forceinline__ float2 wexp_neg(float frac) {
    float rv = -frac;
    rv -= floorf(rv);
    return make_float2(__builtin_amdgcn_cosf(rv), __builtin_amdgcn_sinf(rv));
}
__device__ __forceinline__ unsigned pack_bf2(float a, float b) {
    // D[15:0]=bf16(a), D[31:16]=bf16(b) — single VALU op (RNE)
    unsigned r;
    asm("v_cvt_pk_bf16_f32 %0, %1, %2" : "=v"(r) : "v"(a), "v"(b));
    return r;
}
__device__ __forceinline__ float2 unpack_bf2(unsigned v) {
    return make_float2(__uint_as_float(v << 16), __uint_as_float(v & 0xffff0000u));
}
__device__ __forceinline__ float2 cmul(float2 a, float2 b) {
    return make_float2(fmaf(a.x, b.x, -a.y * b.y), fmaf(a.x, b.y, a.y * b.x));
}
__device__ __forceinline__ float2 cmulc(float2 a, float wr, float wi) {
    return make_float2(fmaf(a.x, wr, -a.y * wi), fmaf(a.x, wi, a.y * wr));
}
__device__ __forceinline__ float2 cadd(float2 a, float2 b) {
    return make_float2(a.x + b.x, a.y + b.y);
}
__device__ __forceinline__ float2 csub(float2 a, float2 b) {
    return make_float2(a.x - b.x, a.y - b.y);
}
__device__ __forceinline__ void cfma(float& acc, float c, float v) {
    if (c == 0.f) return;
    if (c == 1.f)  { acc += v; return; }
    if (c == -1.f) { acc -= v; return; }
    acc = fmaf(c, v, acc);
}

// 8-pt forward DFT via conjugate-symmetric pairs.
__device__ __forceinline__ void dft8_sym(const float2* u, float2* X) {
    float2 a1 = cadd(u[1], u[7]), b1 = csub(u[1], u[7]);
    float2 a2 = cadd(u[2], u[6]), b2 = csub(u[2], u[6]);
    float2 a3 = cadd(u[3], u[5]), b3 = csub(u[3], u[5]);
    float2 s04 = cadd(u[0], u[4]), d04 = csub(u[0], u[4]);
    X[0] = cadd(cadd(s04, a1), cadd(a2, a3));
    X[4] = cadd(csub(s04, a1), csub(a2, a3));
    {
        float2 p = csub(s04, a2);
        float2 q = csub(b1, b3);
        X[2] = make_float2(p.x + q.y, p.y - q.x);
        X[6] = make_float2(p.x - q.y, p.y + q.x);
    }
#pragma unroll
    for (int m = 1; m <= 3; m += 2) {
        float Px = d04.x, Py = d04.y, Qx = 0.f, Qy = 0.f;
#pragma unroll
        for (int n = 1; n <= 3; n++) {
            const float cR = W16R[(2 * n * m) & 15], cI = W16I[(2 * n * m) & 15];
            const float2 a = (n == 1) ? a1 : (n == 2) ? a2 : a3;
            const float2 b = (n == 1) ? b1 : (n == 2) ? b2 : b3;
            cfma(Px, cR, a.x); cfma(Py, cR, a.y);
            cfma(Qx, cI, b.x); cfma(Qy, cI, b.y);
        }
        X[m]     = make_float2(Px - Qy, Py + Qx);
        X[8 - m] = make_float2(Px + Qy, Py - Qx);
    }
}

// 7-pt forward DFT via conjugate-symmetric pairs.
__device__ __forceinline__ void dft7_sym(const float2* x, float2* X) {
    float2 a1 = cadd(x[1], x[6]), b1 = csub(x[1], x[6]);
    float2 a2 = cadd(x[2], x[5]), b2 = csub(x[2], x[5]);
    float2 a3 = cadd(x[3], x[4]), b3 = csub(x[3], x[4]);
    X[0] = cadd(cadd(x[0], a1), cadd(a2, a3));
#pragma unroll
    for (int k = 1; k <= 3; k++) {
        float Px = x[0].x, Py = x[0].y, Qx = 0.f, Qy = 0.f;
#pragma unroll
        for (int n = 1; n <= 3; n++) {
            const float cR = W7R[(n * k) % 7], cI = W7I[(n * k) % 7];
            const float2 a = (n == 1) ? a1 : (n == 2) ? a2 : a3;
            const float2 b = (n == 1) ? b1 : (n == 2) ? b2 : b3;
            cfma(Px, cR, a.x); cfma(Py, cR, a.y);
            cfma(Qx, cI, b.x); cfma(Qy, cI, b.y);
        }
        X[k]     = make_float2(Px - Qy, Py + Qx);
        X[7 - k] = make_float2(Px + Qy, Py - Qx);
    }
}

// Inner 224-split: 16-pt DFT (radix-2 + sym-8) + W224^{n1*k} twiddle.
// Source: registers. Dest: LDS, packed bf16x2, slot stride 14*mul dwords.
__device__ __forceinline__ void inner16_core(const float2* xin,
                                             unsigned* __restrict__ xbuf,
                                             int base, int mul, int n1) {
    float2 u[8], v[8];
#pragma unroll
    for (int n = 0; n < 8; n++) {
        u[n] = cadd(xin[n], xin[n + 8]);
        float2 w = csub(xin[n], xin[n + 8]);
        v[n] = (n == 0) ? w : cmulc(w, W16R[n], W16I[n]);
    }
    float2 u1w = wexp_neg((float)n1 * (1.0f / 224.0f));
    float2 u2w = wexp_neg((float)n1 * (1.0f / 112.0f));
    {
        float2 Xe[8];
        dft8_sym(u, Xe);
        float2 cur = make_float2(1.f, 0.f);
#pragma unroll
        for (int m = 0; m < 8; m++) {
            float2 z = (m == 0) ? Xe[0] : cmul(Xe[m], cur);
            xbuf[base + (14 * (2 * m)) * mul] = pack_bf2(z.x, z.y);
            cur = cmul(cur, u2w);
        }
    }
    {
        float2 Xo[8];
        dft8_sym(v, Xo);
        float2 cur = u1w;
#pragma unroll
        for (int m = 0; m < 8; m++) {
            float2 z = cmul(Xo[m], cur);
            xbuf[base + (14 * (2 * m + 1)) * mul] = pack_bf2(z.x, z.y);
            cur = cmul(cur, u2w);
        }
    }
}

// ---------------- k_phase: grid (197, 4). x<196: phase GEMM (32 b each),
// writes packed bf16x2 plane-0 field. x==196: y0 zloss + defocus tables,
// y1..3 mask^2 thirds.
__global__ __launch_bounds__(256) void k_phase(const float* __restrict__ pred,
                                               const float* __restrict__ target,
                                               const float* __restrict__ zern,
                                               const float* __restrict__ mask,
                                               unsigned* __restrict__ field,
                                               float* __restrict__ ws) {
    __shared__ __align__(16) float pl[32 * 36];  // stride 36: 16B-aligned quads
    __shared__ float red[256];
    int t = threadIdx.x;
    if (blockIdx.x == 196) {
        int y = blockIdx.y;
        float s = 0.f;
        if (y == 0) {
            if (t < 224) {           // separable defocus tables (f32 complex)
                float v = lincoord(t);
                float fc = fmaf(2.f * DEFOCUS_RAD, v * v, -DEFOCUS_RAD);
                float fr = 2.f * DEFOCUS_RAD * v * v;
                float sn, cs;
                fast_sincos(fc, &sn, &cs);
                ((float2*)(ws + 16))[t] = make_float2(cs, sn);   // ctab
                fast_sincos(fr, &sn, &cs);
                ((float2*)(ws + 512))[t] = make_float2(cs, sn);  // rtab
            }
            for (int i = t; i < BB * MM; i += 256) {
                float p = pred[i], tg = target[i];
                float dd = p - tg;
                float w = (p * tg < 0.f) ? SIGN_PENALTY : 1.f;
                s = fmaf(dd * dd, w, s);
            }
        } else {
            const int F4 = PP / 4;
            int st = (y - 1) * 4182;
            int en = (y == 3) ? F4 : st + 4182;
            const float4* m4 = (const float4*)mask;
            for (int i = st + t; i < en; i += 256) {
                float4 v = m4[i];
                s = fmaf(v.x, v.x, s); s = fmaf(v.y, v.y, s);
                s = fmaf(v.z, v.z, s); s = fmaf(v.w, v.w, s);
            }
        }
        red[t] = s;
        __syncthreads();
        for (int st = 128; st > 0; st >>= 1) {
            if (t < st) red[t] += red[t + st];
            __syncthreads();
        }
        if (t == 0) {
            if (y == 0) ws[1] = red[0] / (float)(BB * MM);
            else        ws[1 + y] = red[0];
        }
        return;
    }
    int bg = blockIdx.y;
    for (int i = t; i < 32 * MM; i += 256) {
        int j = i / MM, m = i - (i / MM) * MM;
        pl[j * 36 + m] = pred[(bg * 32 + j) * MM + m];
    }
    if (t < 32) pl[t * 36 + 35] = 0.f;   // pad slot (never multiplied)
    __syncthreads();
    int pix = blockIdx.x * 256 + t;
    float acc[32];
#pragma unroll
    for (int j = 0; j < 32; j++) acc[j] = 0.f;
    const float4* pl4 = (const float4*)pl;     // pl4[j*9 + mb/4]
    for (int mb = 0; mb < 32; mb += 4) {       // 8 chunks of 4 modes
        float z0 = zern[(size_t)(mb + 0) * PP + pix];
        float z1 = zern[(size_t)(mb + 1) * PP + pix];
        float z2 = zern[(size_t)(mb + 2) * PP + pix];
        float z3 = zern[(size_t)(mb + 3) * PP + pix];
#pragma unroll
        for (int j = 0; j < 32; j++) {
            float4 p4 = pl4[j * 9 + (mb >> 2)];
            acc[j] = fmaf(p4.x, z0, acc[j]);
            acc[j] = fmaf(p4.y, z1, acc[j]);
            acc[j] = fmaf(p4.z, z2, acc[j]);
            acc[j] = fmaf(p4.w, z3, acc[j]);
        }
    }
    {                                          // tail: modes 32..34
        float z0 = zern[(size_t)32 * PP + pix];
        float z1 = zern[(size_t)33 * PP + pix];
        float z2 = zern[(size_t)34 * PP + pix];
#pragma unroll
        for (int j = 0; j < 32; j++) {
            float4 p4 = pl4[j * 9 + 8];
            acc[j] = fmaf(p4.x, z0, acc[j]);
            acc[j] = fmaf(p4.y, z1, acc[j]);
            acc[j] = fmaf(p4.z, z2, acc[j]);
        }
    }
    float mk = mask[pix];
#pragma unroll
    for (int j = 0; j < 32; j++) {
        float ph = acc[j] * mk;
        float sn, cs;
        fast_sincos(ph, &sn, &cs);
        field[(size_t)(bg * 32 + j) * PP + pix] = pack_bf2(mk * cs, mk * sn);
    }
}

// ---------------- stage 1: row DFTs, ONE plane per block, ONE barrier -------
// grid (14, 2, BB): d adjacent in dispatch for L2 field reuse. Inner thread
// (r,n1) loads its 16 pixels; d=1 rotates by ctab[col]*rtab[row] (8 FMA/px,
// f32). Single LDS buffer 14.9KB; (256,5) -> 5 blocks/CU.
__global__ __launch_bounds__(256, 5) void k_stage1(const unsigned* __restrict__ field,
                                                   const float* __restrict__ ws,
                                                   unsigned* __restrict__ T) {
    __shared__ unsigned xs[16 * S1];
    int h0 = blockIdx.x * 16;
    int d = blockIdx.y, b = blockIdx.z;
    int t = threadIdx.x;

    if (t < 224) {
        int r = t / 14, n1 = t - (t / 14) * 14;
        const unsigned* frow = field + (size_t)b * PP + (size_t)(h0 + r) * PSZ;
        float2 x0[16];
        if (d) {
            const float2* ctab = (const float2*)(ws + 16);
            const float2* rtab = (const float2*)(ws + 512);
            float2 crow = rtab[h0 + r];
#pragma unroll
            for (int n = 0; n < 16; n++) {
                int col = n1 + 14 * n;
                float2 f = unpack_bf2(frow[col]);
                float2 rot = cmul(crow, ctab[col]);
                x0[n] = cmul(rot, f);
            }
        } else {
#pragma unroll
            for (int n = 0; n < 16; n++) x0[n] = unpack_bf2(frow[n1 + 14 * n]);
        }
        inner16_core(x0, xs, r * S1 + n1, 1, n1);
    }
    __syncthreads();

    {                                 // outer: 16 rows x 16 k2, one plane
        int r = t >> 4, k2 = t & 15;
        const unsigned* xr = xs + r * S1 + k2 * 14;
        int img = d * BB + b;
        // tile-major: T[img][k1][h0+r][k2]
        unsigned* Tt = T + (((size_t)img * 14) * PSZ + (h0 + r)) * 16 + k2;
        float2 e[7], E[7], O[7];
#pragma unroll
        for (int n = 0; n < 7; n++) e[n] = unpack_bf2(xr[2 * n]);
        dft7_sym(e, E);
#pragma unroll
        for (int n = 0; n < 7; n++) e[n] = unpack_bf2(xr[2 * n + 1]);
        dft7_sym(e, O);
#pragma unroll
        for (int k1 = 0; k1 < 7; k1++) {
            float2 op = (k1 == 0) ? O[0] : cmulc(O[k1], W14R[k1], W14I[k1]);
            float2 s = cadd(E[k1], op), q = csub(E[k1], op);
            Tt[(size_t)k1 * (PSZ * 16)]       = pack_bf2(s.x, s.y);
            Tt[(size_t)(k1 + 7) * (PSZ * 16)] = pack_bf2(q.x, q.y);
        }
    }
}

// ---------------- stage 2: column DFTs + in-register psf loss ----------------
// Inner DFT reads tile-major T directly from global (coalesced, LLC-hit),
// writes to LDS; outer consumes LDS transposed. T loads issued first.
__global__ __launch_bounds__(256, 5) void k_stage2(const unsigned* __restrict__ T,
                                                   const float* __restrict__ psfs,
                                                   const float* __restrict__ ws,
                                                   float* __restrict__ partials) {
    __shared__ unsigned xs[224 * S2];
    __shared__ float red[4];
    int tile = blockIdx.x, b = blockIdx.y, d = blockIdx.z;
    int img = d * BB + b;
    int t = threadIdx.x;
    int k2o = t >> 4, c = t & 15;
    bool act = t < 224;

    const unsigned* Tb = T + ((size_t)img * 14 + tile) * (PSZ * 16);
    const float* inp = psfs + ((size_t)b * 2 + d) * PP;
    int scol = 16 * ((tile + 7) % 14) + c;

    unsigned xr[16];                  // T loads first: they gate the barrier
    if (act) {
#pragma unroll
        for (int n = 0; n < 16; n++) xr[n] = Tb[224 * n + t];
    }
    float pf[14];
#pragma unroll
    for (int j = 0; j < 7; j++) {
        pf[j]     = inp[(size_t)(112 + 16 * j + k2o) * PSZ + scol];
        pf[j + 7] = inp[(size_t)(16 * j + k2o) * PSZ + scol];
    }

    if (act) {                        // inner: 14 n1 x 16 c, reg -> LDS
        float2 x[16];
#pragma unroll
        for (int n = 0; n < 16; n++) x[n] = unpack_bf2(xr[n]);
        inner16_core(x, xs, (t >> 4) * S2 + (t & 15), S2, t >> 4);
    }
    __syncthreads();

    float m2 = ws[2] + ws[3] + ws[4];
    float inv_denom = 1.f / (m2 * (float)PP + EPS_F);  // Parseval denominator

    float lsum = 0.f;
    {                                 // outer: 16 k2 x 16 c, loss in-register
        float2 e[7], E[7], O[7];
#pragma unroll
        for (int n = 0; n < 7; n++) e[n] = unpack_bf2(xs[(k2o * 14 + 2 * n) * S2 + c]);
        dft7_sym(e, E);
#pragma unroll
        for (int n = 0; n < 7; n++) e[n] = unpack_bf2(xs[(k2o * 14 + 2 * n + 1) * S2 + c]);
        dft7_sym(e, O);
#pragma unroll
        for (int k1 = 0; k1 < 7; k1++) {
            float2 op = (k1 == 0) ? O[0] : cmulc(O[k1], W14R[k1], W14I[k1]);
            float2 s = cadd(E[k1], op), q = csub(E[k1], op);
            float ds = fmaf(s.x, s.x, s.y * s.y) * inv_denom - pf[k1];
            float dq = fmaf(q.x, q.x, q.y * q.y) * inv_denom - pf[k1 + 7];
            lsum = fmaf(ds, ds, lsum);
            lsum = fmaf(dq, dq, lsum);
        }
    }
#pragma unroll
    for (int off = 32; off > 0; off >>= 1)
        lsum += __shfl_down(lsum, off, 64);
    if ((t & 63) == 0) red[t >> 6] = lsum;
    __syncthreads();
    if (t == 0)
        partials[(blockIdx.z * BB + blockIdx.y) * 14 + blockIdx.x] =
            red[0] + red[1] + red[2] + red[3];
}

// ---------------- final ----------------
__global__ void k_final(const float* __restrict__ ws,
                        const float* __restrict__ partials,
                        float* __restrict__ out) {
    __shared__ float red[256];
    float s = 0.f;
    for (int i = threadIdx.x; i < N_PARTIALS; i += 256) s += partials[i];
    red[threadIdx.x] = s;
    __syncthreads();
    for (int st = 128; st > 0; st >>= 1) {
        if (threadIdx.x < st) red[threadIdx.x] += red[threadIdx.x + st];
        __syncthreads();
    }
    if (threadIdx.x == 0) {
        float recon = red[0] / (float)((size_t)BB * PP);
        out[0] = ws[1] + RECON_WEIGHT * recon;
    }
}

extern "C" void kernel_launch(void* const* d_in, const int* in_sizes, int n_in,
                              void* d_out, int out_size, void* d_ws, size_t ws_size,
                              hipStream_t stream) {
    const float* pred   = (const float*)d_in[0];
    const float* target = (const float*)d_in[1];
    const float* psfs   = (const float*)d_in[2];
    const float* zern   = (const float*)d_in[3];
    const float* mask   = (const float*)d_in[4];

    float*    ws       = (float*)d_ws;
    unsigned* field    = (unsigned*)(ws + WS_PHASE_OFF);
    float*    partials = ws + WS_PHASE_OFF;   // aliases field (dead after stage1)
    unsigned* T        = (unsigned*)(ws + WS_T_OFF);
    float*    out      = (float*)d_out;

    k_phase<<<dim3(197, 4), 256, 0, stream>>>(pred, target, zern, mask, field, ws);
    k_stage1<<<dim3(14, 2, BB), 256, 0, stream>>>(field, ws, T);
    k_stage2<<<dim3(14, BB, 2), 256, 0, stream>>>(T, psfs, ws, partials);
    k_final<<<1, 256, 0, stream>>>(ws, partials, out);
}

// Round 5
// 152.291 us; speedup vs baseline: 1.1842x; 1.0048x over previous
//
#include <hip/hip_runtime.h>
#include <math.h>

#define BB 128
#define MM 35
#define PSZ 224
#define PP (PSZ*PSZ)          // 50176
#define SIGN_PENALTY 10.0f
#define RECON_WEIGHT 0.4f
#define DEFOCUS_RAD 1.0f
#define EPS_F 1e-8f
#define INV2PI 0.15915494309189535f

// CT: 224 = 14*16.  n = 14*n2 + n1; k = 16*k1 + k2.
// R17 = R16 + k_phase pixel-blocking:
//   k_phase: 128 threads/block, 2 pixels/thread (grid unchanged 197x4,
//            same 256-px tiles -> same 784-block balance). The 288
//            ds_read_b128 of pl4 per thread now serve TWO pixels -> total
//            LDS issue halves (57.8M -> 28.9M b128, ~17.6 -> ~8.8 us).
//            acc0[32]+acc1[32]=64 VGPR + 8 z + temps ~ 90 VGPR, no spill.
// Budget model (R16 post-mortem): 256MiB harness poison fills (~41us each,
// fixed) sit in the timed window; our kernels sum ~70-110us. k_phase was the
// largest controllable block (LDS-issue-bound).
// Prior structure: separable defocus tables (ws[16..960)); stage1 one plane
// per block grid (14,2,BB), (256,5); tile-major T [img][tile14][h224][c16];
// stage2 global-direct + in-reg loss; v_cvt_pk_bf16_f32 packing.
// Spill rule (R10/R11): >~32 floats cross-phase state = scratch.
// Atomic rule (R5-R7): no same-address finale atomics.

// ws layout (floats):
//   [1] z_loss  [2..4] mask^2 partials (3)
//   [16..464)  ctab: 224 x float2 e^{i(2D vx^2 - D)}
//   [512..960) rtab: 224 x float2 e^{i(2D vy^2)}
//   [2048 ..) field [B][P][P] packed bf16x2 — dead after stage1; partials alias
//   [T_OFF ..) T [2*B][14][224][16] packed bf16x2
#define WS_PHASE_OFF    2048
#define WS_T_OFF        (WS_PHASE_OFF + BB*PP)
#define N_PARTIALS      (14*BB*2)
#define S1 233            // stage1 LDS row stride (dwords) — odd: 2-way banks
#define S2 20             // stage2 LDS slot-row stride (dwords)

static constexpr float W16R[16] = {
    1.0f, 0.9238795325f, 0.7071067812f, 0.3826834324f, 0.0f,
    -0.3826834324f, -0.7071067812f, -0.9238795325f, -1.0f,
    -0.9238795325f, -0.7071067812f, -0.3826834324f, 0.0f,
    0.3826834324f, 0.7071067812f, 0.9238795325f};
static constexpr float W16I[16] = {
    0.0f, -0.3826834324f, -0.7071067812f, -0.9238795325f, -1.0f,
    -0.9238795325f, -0.7071067812f, -0.3826834324f, 0.0f,
    0.3826834324f, 0.7071067812f, 0.9238795325f, 1.0f,
    0.9238795325f, 0.7071067812f, 0.3826834324f};
static constexpr float W7R[7] = {
    1.0f, 0.6234898019f, -0.2225209340f, -0.9009688679f,
    -0.9009688679f, -0.2225209340f, 0.6234898019f};
static constexpr float W7I[7] = {
    0.0f, -0.7818314825f, -0.9749279122f, -0.4338837391f,
    0.4338837391f, 0.9749279122f, 0.7818314825f};
static constexpr float W14R[7] = {
    1.0f, 0.9009688679f, 0.6234898019f, 0.2225209340f, -0.2225209340f,
    -0.6234898019f, -0.9009688679f};
static constexpr float W14I[7] = {
    0.0f, -0.4338837391f, -0.7818314825f, -0.9749279122f, -0.9749279122f,
    -0.7818314825f, -0.4338837391f};

__device__ __forceinline__ float lincoord(int i) {
    return -1.0f + 2.0f * (float)i / (float)(PSZ - 1);
}
__device__ __forceinline__ void fast_sincos(float x, float* s, float* c) {
    float rv = x * INV2PI;
    rv -= floorf(rv);
    *s = __builtin_amdgcn_sinf(rv);
    *c = __builtin_amdgcn_cosf(rv);
}
__device__ __forceinline__ float2 wexp_neg(float frac) {
    float rv = -frac;
    rv -= floorf(rv);
    return make_float2(__builtin_amdgcn_cosf(rv), __builtin_amdgcn_sinf(rv));
}
__device__ __forceinline__ unsigned pack_bf2(float a, float b) {
    // D[15:0]=bf16(a), D[31:16]=bf16(b) — single VALU op (RNE)
    unsigned r;
    asm("v_cvt_pk_bf16_f32 %0, %1, %2" : "=v"(r) : "v"(a), "v"(b));
    return r;
}
__device__ __forceinline__ float2 unpack_bf2(unsigned v) {
    return make_float2(__uint_as_float(v << 16), __uint_as_float(v & 0xffff0000u));
}
__device__ __forceinline__ float2 cmul(float2 a, float2 b) {
    return make_float2(fmaf(a.x, b.x, -a.y * b.y), fmaf(a.x, b.y, a.y * b.x));
}
__device__ __forceinline__ float2 cmulc(float2 a, float wr, float wi) {
    return make_float2(fmaf(a.x, wr, -a.y * wi), fmaf(a.x, wi, a.y * wr));
}
__device__ __forceinline__ float2 cadd(float2 a, float2 b) {
    return make_float2(a.x + b.x, a.y + b.y);
}
__device__ __forceinline__ float2 csub(float2 a, float2 b) {
    return make_float2(a.x - b.x, a.y - b.y);
}
__device__ __forceinline__ void cfma(float& acc, float c, float v) {
    if (c == 0.f) return;
    if (c == 1.f)  { acc += v; return; }
    if (c == -1.f) { acc -= v; return; }
    acc = fmaf(c, v, acc);
}

// 8-pt forward DFT via conjugate-symmetric pairs.
__device__ __forceinline__ void dft8_sym(const float2* u, float2* X) {
    float2 a1 = cadd(u[1], u[7]), b1 = csub(u[1], u[7]);
    float2 a2 = cadd(u[2], u[6]), b2 = csub(u[2], u[6]);
    float2 a3 = cadd(u[3], u[5]), b3 = csub(u[3], u[5]);
    float2 s04 = cadd(u[0], u[4]), d04 = csub(u[0], u[4]);
    X[0] = cadd(cadd(s04, a1), cadd(a2, a3));
    X[4] = cadd(csub(s04, a1), csub(a2, a3));
    {
        float2 p = csub(s04, a2);
        float2 q = csub(b1, b3);
        X[2] = make_float2(p.x + q.y, p.y - q.x);
        X[6] = make_float2(p.x - q.y, p.y + q.x);
    }
#pragma unroll
    for (int m = 1; m <= 3; m += 2) {
        float Px = d04.x, Py = d04.y, Qx = 0.f, Qy = 0.f;
#pragma unroll
        for (int n = 1; n <= 3; n++) {
            const float cR = W16R[(2 * n * m) & 15], cI = W16I[(2 * n * m) & 15];
            const float2 a = (n == 1) ? a1 : (n == 2) ? a2 : a3;
            const float2 b = (n == 1) ? b1 : (n == 2) ? b2 : b3;
            cfma(Px, cR, a.x); cfma(Py, cR, a.y);
            cfma(Qx, cI, b.x); cfma(Qy, cI, b.y);
        }
        X[m]     = make_float2(Px - Qy, Py + Qx);
        X[8 - m] = make_float2(Px + Qy, Py - Qx);
    }
}

// 7-pt forward DFT via conjugate-symmetric pairs.
__device__ __forceinline__ void dft7_sym(const float2* x, float2* X) {
    float2 a1 = cadd(x[1], x[6]), b1 = csub(x[1], x[6]);
    float2 a2 = cadd(x[2], x[5]), b2 = csub(x[2], x[5]);
    float2 a3 = cadd(x[3], x[4]), b3 = csub(x[3], x[4]);
    X[0] = cadd(cadd(x[0], a1), cadd(a2, a3));
#pragma unroll
    for (int k = 1; k <= 3; k++) {
        float Px = x[0].x, Py = x[0].y, Qx = 0.f, Qy = 0.f;
#pragma unroll
        for (int n = 1; n <= 3; n++) {
            const float cR = W7R[(n * k) % 7], cI = W7I[(n * k) % 7];
            const float2 a = (n == 1) ? a1 : (n == 2) ? a2 : a3;
            const float2 b = (n == 1) ? b1 : (n == 2) ? b2 : b3;
            cfma(Px, cR, a.x); cfma(Py, cR, a.y);
            cfma(Qx, cI, b.x); cfma(Qy, cI, b.y);
        }
        X[k]     = make_float2(Px - Qy, Py + Qx);
        X[7 - k] = make_float2(Px + Qy, Py - Qx);
    }
}

// Inner 224-split: 16-pt DFT (radix-2 + sym-8) + W224^{n1*k} twiddle.
// Source: registers. Dest: LDS, packed bf16x2, slot stride 14*mul dwords.
__device__ __forceinline__ void inner16_core(const float2* xin,
                                             unsigned* __restrict__ xbuf,
                                             int base, int mul, int n1) {
    float2 u[8], v[8];
#pragma unroll
    for (int n = 0; n < 8; n++) {
        u[n] = cadd(xin[n], xin[n + 8]);
        float2 w = csub(xin[n], xin[n + 8]);
        v[n] = (n == 0) ? w : cmulc(w, W16R[n], W16I[n]);
    }
    float2 u1w = wexp_neg((float)n1 * (1.0f / 224.0f));
    float2 u2w = wexp_neg((float)n1 * (1.0f / 112.0f));
    {
        float2 Xe[8];
        dft8_sym(u, Xe);
        float2 cur = make_float2(1.f, 0.f);
#pragma unroll
        for (int m = 0; m < 8; m++) {
            float2 z = (m == 0) ? Xe[0] : cmul(Xe[m], cur);
            xbuf[base + (14 * (2 * m)) * mul] = pack_bf2(z.x, z.y);
            cur = cmul(cur, u2w);
        }
    }
    {
        float2 Xo[8];
        dft8_sym(v, Xo);
        float2 cur = u1w;
#pragma unroll
        for (int m = 0; m < 8; m++) {
            float2 z = cmul(Xo[m], cur);
            xbuf[base + (14 * (2 * m + 1)) * mul] = pack_bf2(z.x, z.y);
            cur = cmul(cur, u2w);
        }
    }
}

// ---------------- k_phase: grid (197, 4), 128 threads. x<196: phase GEMM,
// 2 pixels/thread (same 256-px tile), writes packed bf16x2 plane-0 field.
// x==196: y0 zloss + defocus tables, y1..3 mask^2 thirds.
__global__ __launch_bounds__(128) void k_phase(const float* __restrict__ pred,
                                               const float* __restrict__ target,
                                               const float* __restrict__ zern,
                                               const float* __restrict__ mask,
                                               unsigned* __restrict__ field,
                                               float* __restrict__ ws) {
    __shared__ __align__(16) float pl[32 * 36];  // stride 36: 16B-aligned quads
    __shared__ float red[128];
    int t = threadIdx.x;
    if (blockIdx.x == 196) {
        int y = blockIdx.y;
        float s = 0.f;
        if (y == 0) {
            for (int i = t; i < 224; i += 128) {  // separable defocus tables
                float v = lincoord(i);
                float fc = fmaf(2.f * DEFOCUS_RAD, v * v, -DEFOCUS_RAD);
                float fr = 2.f * DEFOCUS_RAD * v * v;
                float sn, cs;
                fast_sincos(fc, &sn, &cs);
                ((float2*)(ws + 16))[i] = make_float2(cs, sn);   // ctab
                fast_sincos(fr, &sn, &cs);
                ((float2*)(ws + 512))[i] = make_float2(cs, sn);  // rtab
            }
            for (int i = t; i < BB * MM; i += 128) {
                float p = pred[i], tg = target[i];
                float dd = p - tg;
                float w = (p * tg < 0.f) ? SIGN_PENALTY : 1.f;
                s = fmaf(dd * dd, w, s);
            }
        } else {
            const int F4 = PP / 4;
            int st = (y - 1) * 4182;
            int en = (y == 3) ? F4 : st + 4182;
            const float4* m4 = (const float4*)mask;
            for (int i = st + t; i < en; i += 128) {
                float4 v = m4[i];
                s = fmaf(v.x, v.x, s); s = fmaf(v.y, v.y, s);
                s = fmaf(v.z, v.z, s); s = fmaf(v.w, v.w, s);
            }
        }
        red[t] = s;
        __syncthreads();
        for (int st = 64; st > 0; st >>= 1) {
            if (t < st) red[t] += red[t + st];
            __syncthreads();
        }
        if (t == 0) {
            if (y == 0) ws[1] = red[0] / (float)(BB * MM);
            else        ws[1 + y] = red[0];
        }
        return;
    }
    int bg = blockIdx.y;
    for (int i = t; i < 32 * MM; i += 128) {
        int j = i / MM, m = i - (i / MM) * MM;
        pl[j * 36 + m] = pred[(bg * 32 + j) * MM + m];
    }
    if (t < 32) pl[t * 36 + 35] = 0.f;   // pad slot (never multiplied)
    __syncthreads();
    int pix0 = blockIdx.x * 256 + t;     // t in 0..127
    int pix1 = pix0 + 128;
    float acc0[32], acc1[32];
#pragma unroll
    for (int j = 0; j < 32; j++) { acc0[j] = 0.f; acc1[j] = 0.f; }
    const float4* pl4 = (const float4*)pl;     // pl4[j*9 + mb/4]
    for (int mb = 0; mb < 32; mb += 4) {       // 8 chunks of 4 modes
        float z0 = zern[(size_t)(mb + 0) * PP + pix0];
        float z1 = zern[(size_t)(mb + 1) * PP + pix0];
        float z2 = zern[(size_t)(mb + 2) * PP + pix0];
        float z3 = zern[(size_t)(mb + 3) * PP + pix0];
        float w0 = zern[(size_t)(mb + 0) * PP + pix1];
        float w1 = zern[(size_t)(mb + 1) * PP + pix1];
        float w2 = zern[(size_t)(mb + 2) * PP + pix1];
        float w3 = zern[(size_t)(mb + 3) * PP + pix1];
#pragma unroll
        for (int j = 0; j < 32; j++) {
            float4 p4 = pl4[j * 9 + (mb >> 2)];
            acc0[j] = fmaf(p4.x, z0, acc0[j]);
            acc0[j] = fmaf(p4.y, z1, acc0[j]);
            acc0[j] = fmaf(p4.z, z2, acc0[j]);
            acc0[j] = fmaf(p4.w, z3, acc0[j]);
            acc1[j] = fmaf(p4.x, w0, acc1[j]);
            acc1[j] = fmaf(p4.y, w1, acc1[j]);
            acc1[j] = fmaf(p4.z, w2, acc1[j]);
            acc1[j] = fmaf(p4.w, w3, acc1[j]);
        }
    }
    {                                          // tail: modes 32..34
        float z0 = zern[(size_t)32 * PP + pix0];
        float z1 = zern[(size_t)33 * PP + pix0];
        float z2 = zern[(size_t)34 * PP + pix0];
        float w0 = zern[(size_t)32 * PP + pix1];
        float w1 = zern[(size_t)33 * PP + pix1];
        float w2 = zern[(size_t)34 * PP + pix1];
#pragma unroll
        for (int j = 0; j < 32; j++) {
            float4 p4 = pl4[j * 9 + 8];
            acc0[j] = fmaf(p4.x, z0, acc0[j]);
            acc0[j] = fmaf(p4.y, z1, acc0[j]);
            acc0[j] = fmaf(p4.z, z2, acc0[j]);
            acc1[j] = fmaf(p4.x, w0, acc1[j]);
            acc1[j] = fmaf(p4.y, w1, acc1[j]);
            acc1[j] = fmaf(p4.z, w2, acc1[j]);
        }
    }
    float mk0 = mask[pix0], mk1 = mask[pix1];
#pragma unroll
    for (int j = 0; j < 32; j++) {
        size_t row = (size_t)(bg * 32 + j) * PP;
        float sn, cs;
        fast_sincos(acc0[j] * mk0, &sn, &cs);
        field[row + pix0] = pack_bf2(mk0 * cs, mk0 * sn);
        fast_sincos(acc1[j] * mk1, &sn, &cs);
        field[row + pix1] = pack_bf2(mk1 * cs, mk1 * sn);
    }
}

// ---------------- stage 1: row DFTs, ONE plane per block, ONE barrier -------
// grid (14, 2, BB): d adjacent in dispatch for L2 field reuse. Inner thread
// (r,n1) loads its 16 pixels; d=1 rotates by ctab[col]*rtab[row] (8 FMA/px,
// f32). Single LDS buffer 14.9KB; (256,5) -> 5 blocks/CU.
__global__ __launch_bounds__(256, 5) void k_stage1(const unsigned* __restrict__ field,
                                                   const float* __restrict__ ws,
                                                   unsigned* __restrict__ T) {
    __shared__ unsigned xs[16 * S1];
    int h0 = blockIdx.x * 16;
    int d = blockIdx.y, b = blockIdx.z;
    int t = threadIdx.x;

    if (t < 224) {
        int r = t / 14, n1 = t - (t / 14) * 14;
        const unsigned* frow = field + (size_t)b * PP + (size_t)(h0 + r) * PSZ;
        float2 x0[16];
        if (d) {
            const float2* ctab = (const float2*)(ws + 16);
            const float2* rtab = (const float2*)(ws + 512);
            float2 crow = rtab[h0 + r];
#pragma unroll
            for (int n = 0; n < 16; n++) {
                int col = n1 + 14 * n;
                float2 f = unpack_bf2(frow[col]);
                float2 rot = cmul(crow, ctab[col]);
                x0[n] = cmul(rot, f);
            }
        } else {
#pragma unroll
            for (int n = 0; n < 16; n++) x0[n] = unpack_bf2(frow[n1 + 14 * n]);
        }
        inner16_core(x0, xs, r * S1 + n1, 1, n1);
    }
    __syncthreads();

    {                                 // outer: 16 rows x 16 k2, one plane
        int r = t >> 4, k2 = t & 15;
        const unsigned* xr = xs + r * S1 + k2 * 14;
        int img = d * BB + b;
        // tile-major: T[img][k1][h0+r][k2]
        unsigned* Tt = T + (((size_t)img * 14) * PSZ + (h0 + r)) * 16 + k2;
        float2 e[7], E[7], O[7];
#pragma unroll
        for (int n = 0; n < 7; n++) e[n] = unpack_bf2(xr[2 * n]);
        dft7_sym(e, E);
#pragma unroll
        for (int n = 0; n < 7; n++) e[n] = unpack_bf2(xr[2 * n + 1]);
        dft7_sym(e, O);
#pragma unroll
        for (int k1 = 0; k1 < 7; k1++) {
            float2 op = (k1 == 0) ? O[0] : cmulc(O[k1], W14R[k1], W14I[k1]);
            float2 s = cadd(E[k1], op), q = csub(E[k1], op);
            Tt[(size_t)k1 * (PSZ * 16)]       = pack_bf2(s.x, s.y);
            Tt[(size_t)(k1 + 7) * (PSZ * 16)] = pack_bf2(q.x, q.y);
        }
    }
}

// ---------------- stage 2: column DFTs + in-register psf loss ----------------
// Inner DFT reads tile-major T directly from global (coalesced, LLC-hit),
// writes to LDS; outer consumes LDS transposed. T loads issued first.
__global__ __launch_bounds__(256, 5) void k_stage2(const unsigned* __restrict__ T,
                                                   const float* __restrict__ psfs,
                                                   const float* __restrict__ ws,
                                                   float* __restrict__ partials) {
    __shared__ unsigned xs[224 * S2];
    __shared__ float red[4];
    int tile = blockIdx.x, b = blockIdx.y, d = blockIdx.z;
    int img = d * BB + b;
    int t = threadIdx.x;
    int k2o = t >> 4, c = t & 15;
    bool act = t < 224;

    const unsigned* Tb = T + ((size_t)img * 14 + tile) * (PSZ * 16);
    const float* inp = psfs + ((size_t)b * 2 + d) * PP;
    int scol = 16 * ((tile + 7) % 14) + c;

    unsigned xr[16];                  // T loads first: they gate the barrier
    if (act) {
#pragma unroll
        for (int n = 0; n < 16; n++) xr[n] = Tb[224 * n + t];
    }
    float pf[14];
#pragma unroll
    for (int j = 0; j < 7; j++) {
        pf[j]     = inp[(size_t)(112 + 16 * j + k2o) * PSZ + scol];
        pf[j + 7] = inp[(size_t)(16 * j + k2o) * PSZ + scol];
    }

    if (act) {                        // inner: 14 n1 x 16 c, reg -> LDS
        float2 x[16];
#pragma unroll
        for (int n = 0; n < 16; n++) x[n] = unpack_bf2(xr[n]);
        inner16_core(x, xs, (t >> 4) * S2 + (t & 15), S2, t >> 4);
    }
    __syncthreads();

    float m2 = ws[2] + ws[3] + ws[4];
    float inv_denom = 1.f / (m2 * (float)PP + EPS_F);  // Parseval denominator

    float lsum = 0.f;
    {                                 // outer: 16 k2 x 16 c, loss in-register
        float2 e[7], E[7], O[7];
#pragma unroll
        for (int n = 0; n < 7; n++) e[n] = unpack_bf2(xs[(k2o * 14 + 2 * n) * S2 + c]);
        dft7_sym(e, E);
#pragma unroll
        for (int n = 0; n < 7; n++) e[n] = unpack_bf2(xs[(k2o * 14 + 2 * n + 1) * S2 + c]);
        dft7_sym(e, O);
#pragma unroll
        for (int k1 = 0; k1 < 7; k1++) {
            float2 op = (k1 == 0) ? O[0] : cmulc(O[k1], W14R[k1], W14I[k1]);
            float2 s = cadd(E[k1], op), q = csub(E[k1], op);
            float ds = fmaf(s.x, s.x, s.y * s.y) * inv_denom - pf[k1];
            float dq = fmaf(q.x, q.x, q.y * q.y) * inv_denom - pf[k1 + 7];
            lsum = fmaf(ds, ds, lsum);
            lsum = fmaf(dq, dq, lsum);
        }
    }
#pragma unroll
    for (int off = 32; off > 0; off >>= 1)
        lsum += __shfl_down(lsum, off, 64);
    if ((t & 63) == 0) red[t >> 6] = lsum;
    __syncthreads();
    if (t == 0)
        partials[(blockIdx.z * BB + blockIdx.y) * 14 + blockIdx.x] =
            red[0] + red[1] + red[2] + red[3];
}

// ---------------- final ----------------
__global__ void k_final(const float* __restrict__ ws,
                        const float* __restrict__ partials,
                        float* __restrict__ out) {
    __shared__ float red[256];
    float s = 0.f;
    for (int i = threadIdx.x; i < N_PARTIALS; i += 256) s += partials[i];
    red[threadIdx.x] = s;
    __syncthreads();
    for (int st = 128; st > 0; st >>= 1) {
        if (threadIdx.x < st) red[threadIdx.x] += red[threadIdx.x + st];
        __syncthreads();
    }
    if (threadIdx.x == 0) {
        float recon = red[0] / (float)((size_t)BB * PP);
        out[0] = ws[1] + RECON_WEIGHT * recon;
    }
}

extern "C" void kernel_launch(void* const* d_in, const int* in_sizes, int n_in,
                              void* d_out, int out_size, void* d_ws, size_t ws_size,
                              hipStream_t stream) {
    const float* pred   = (const float*)d_in[0];
    const float* target = (const float*)d_in[1];
    const float* psfs   = (const float*)d_in[2];
    const float* zern   = (const float*)d_in[3];
    const float* mask   = (const float*)d_in[4];

    float*    ws       = (float*)d_ws;
    unsigned* field    = (unsigned*)(ws + WS_PHASE_OFF);
    float*    partials = ws + WS_PHASE_OFF;   // aliases field (dead after stage1)
    unsigned* T        = (unsigned*)(ws + WS_T_OFF);
    float*    out      = (float*)d_out;

    k_phase<<<dim3(197, 4), 128, 0, stream>>>(pred, target, zern, mask, field, ws);
    k_stage1<<<dim3(14, 2, BB), 256, 0, stream>>>(field, ws, T);
    k_stage2<<<dim3(14, BB, 2), 256, 0, stream>>>(T, psfs, ws, partials);
    k_final<<<1, 256, 0, stream>>>(ws, partials, out);
}